// Round 5
// baseline (1150.979 us; speedup 1.0000x reference)
//
#include <hip/hip_runtime.h>
#include <hip/hip_bf16.h>

#define KNN 20
#define NEG_SLOPE 0.2f

constexpr int BB = 8;
constexpr int NN = 1024;
constexpr int MM = 1024;

// ---------------- transpose f32: (B,C,Np) -> (B,Np,C) ----------------
__global__ __launch_bounds__(256) void k_transpose(
    const float* __restrict__ in, float* __restrict__ out, int C, int Np) {
  int total = BB * C * Np;
  for (int t = blockIdx.x * 256 + threadIdx.x; t < total; t += gridDim.x * 256) {
    int c = t % C;
    int n = (t / C) % Np;
    int b = t / (C * Np);
    out[t] = in[((size_t)b * C + c) * Np + n];
  }
}

// ------- per-point squared norm (RECIP=0) or reciprocal norm (RECIP=1), f64 out -------
template <int RECIP>
__global__ __launch_bounds__(256) void k_rowsq(
    const float* __restrict__ A, int ld, int C, double* __restrict__ sq) {
  int p = blockIdx.x * 256 + threadIdx.x;
  if (p >= BB * NN) return;
  const float* row = A + (size_t)p * ld;
  double s = 0.0;
  for (int c = 0; c < C; ++c) { double v = (double)row[c]; s += v * v; }
  if (RECIP) {
    sq[p] = 1.0 / fmax(sqrt(s), 1e-12);
  } else {
    sq[p] = s;
  }
}

// ---------------- batched gram over a CB-batch chunk starting at b0, f64 ----------------
// MODE 1: D = 2*dot - sqA_i - sqB_j   (euclidean knn)
// MODE 2: D = dot * rnA_i * rnB_j     (cosine; sqA/sqB hold reciprocal norms)
template <int MODE>
__global__ __launch_bounds__(256) void k_gram(
    const float* __restrict__ A, int lda, const float* __restrict__ Bm, int ldb,
    const double* __restrict__ sqA, const double* __restrict__ sqB,
    double* __restrict__ D, int C, int b0) {
  __shared__ float As[16][68];
  __shared__ float Bs[16][68];
  int bg = b0 + blockIdx.z;            // global batch
  int bl = blockIdx.z;                 // local batch in chunk
  int i0 = blockIdx.y * 64;
  int j0 = blockIdx.x * 64;
  const float* Ab = A + (size_t)bg * NN * lda;
  const float* Bb = Bm + (size_t)bg * MM * ldb;
  int tx = threadIdx.x, ty = threadIdx.y;
  int tid = ty * 16 + tx;
  double acc[4][4] = {};
  for (int c0 = 0; c0 < C; c0 += 16) {
    for (int r = 0; r < 4; ++r) {
      int li = tid + r * 256;
      int row = li >> 4, k = li & 15;
      int c = c0 + k;
      As[k][row] = (c < C) ? Ab[(size_t)(i0 + row) * lda + c] : 0.f;
      Bs[k][row] = (c < C) ? Bb[(size_t)(j0 + row) * ldb + c] : 0.f;
    }
    __syncthreads();
#pragma unroll
    for (int k = 0; k < 16; ++k) {
      double a_[4], b_[4];
#pragma unroll
      for (int ii = 0; ii < 4; ++ii) a_[ii] = (double)As[k][ty * 4 + ii];
#pragma unroll
      for (int jj = 0; jj < 4; ++jj) b_[jj] = (double)Bs[k][tx * 4 + jj];
#pragma unroll
      for (int ii = 0; ii < 4; ++ii)
#pragma unroll
        for (int jj = 0; jj < 4; ++jj)
          acc[ii][jj] = fma(a_[ii], b_[jj], acc[ii][jj]);
    }
    __syncthreads();
  }
  for (int ii = 0; ii < 4; ++ii) {
    int i = i0 + ty * 4 + ii;
    for (int jj = 0; jj < 4; ++jj) {
      int j = j0 + tx * 4 + jj;
      double r = acc[ii][jj];
      if (MODE == 1) r = 2.0 * r - sqA[bg * NN + i] - sqB[bg * NN + j];
      if (MODE == 2) r = r * sqA[bg * NN + i] * sqB[bg * NN + j];
      D[((size_t)bl * NN + i) * MM + j] = r;
    }
  }
}

// ------- top-20 per row over the chunk, f64 (largest value, tie -> lowest index) -------
__global__ __launch_bounds__(256) void k_topk(const double* __restrict__ D,
                                              int* __restrict__ idx, int b0) {
  int wave = threadIdx.x >> 6;
  int lane = threadIdx.x & 63;
  int p = blockIdx.x * 4 + wave;  // local row in [0, CB*NN)
  const double* row = D + (size_t)p * MM;
  double v[16];
#pragma unroll
  for (int m = 0; m < 16; ++m) v[m] = row[m * 64 + lane];
  int* op = idx + ((size_t)b0 * NN + p) * KNN;
  for (int r = 0; r < KNN; ++r) {
    double bv = -INFINITY;
    int bj = MM;
#pragma unroll
    for (int m = 0; m < 16; ++m) {
      if (v[m] > bv) { bv = v[m]; bj = m * 64 + lane; }
    }
#pragma unroll
    for (int off = 32; off > 0; off >>= 1) {
      double ov = __shfl_xor(bv, off, 64);
      int oj = __shfl_xor(bj, off, 64);
      if (ov > bv || (ov == bv && oj < bj)) { bv = ov; bj = oj; }
    }
    if (bj < MM && lane == (bj & 63)) v[bj >> 6] = -INFINITY;
    if (lane == 0) op[r] = bj;
  }
}

// ------- per-point feature matmul: out[b,j,o] = sum_c src[b,j,c] * weff[o,c] (f32) -------
// mode 0: weff = w[o,c]; mode 1: weff = w[o,C+c] - w[o,c]
__global__ __launch_bounds__(256) void k_featmm(
    const float* __restrict__ src, int lds_, const float* __restrict__ w, int CW,
    float* __restrict__ out, int C, int O, int mode, int Np) {
  __shared__ float As[16][68];
  __shared__ float Ws[16][68];
  int b = blockIdx.z;
  int j0 = blockIdx.y * 64;
  int o0 = blockIdx.x * 64;
  int tx = threadIdx.x, ty = threadIdx.y;
  int tid = ty * 16 + tx;
  const float* Sb = src + (size_t)b * Np * lds_;
  float acc[4][4] = {};
  for (int c0 = 0; c0 < C; c0 += 16) {
    for (int r = 0; r < 4; ++r) {
      int li = tid + r * 256;
      int row = li >> 4, k = li & 15;
      int c = c0 + k;
      As[k][row] = (c < C) ? Sb[(size_t)(j0 + row) * lds_ + c] : 0.f;
      float wv = 0.f;
      if (c < C) {
        const float* wr = w + (size_t)(o0 + row) * CW;
        wv = mode == 0 ? wr[c] : (wr[C + c] - wr[c]);
      }
      Ws[k][row] = wv;
    }
    __syncthreads();
#pragma unroll
    for (int k = 0; k < 16; ++k) {
      float a_[4], b_[4];
#pragma unroll
      for (int ii = 0; ii < 4; ++ii) a_[ii] = As[k][ty * 4 + ii];
#pragma unroll
      for (int jj = 0; jj < 4; ++jj) b_[jj] = Ws[k][tx * 4 + jj];
#pragma unroll
      for (int ii = 0; ii < 4; ++ii)
#pragma unroll
        for (int jj = 0; jj < 4; ++jj)
          acc[ii][jj] = fmaf(a_[ii], b_[jj], acc[ii][jj]);
    }
    __syncthreads();
  }
  for (int ii = 0; ii < 4; ++ii) {
    int j = j0 + ty * 4 + ii;
    float4 v;
    float* vp = &v.x;
    for (int jj = 0; jj < 4; ++jj) vp[jj] = acc[ii][jj];
    *(float4*)&out[((size_t)b * Np + j) * O + o0 + tx * 4] = v;
  }
}

// ---------------- BN stats over y = u[idx]+t (edge layers, O<=256) ----------------
__global__ __launch_bounds__(256) void k_bnstats(
    const float* __restrict__ u, const float* __restrict__ t, const int* __restrict__ idx,
    double* __restrict__ stats, int O, int Np, int Kn, int srcNp) {
  __shared__ int lidx[32 * KNN];
  int b = blockIdx.y;
  int n0 = blockIdx.x * 32;
  int tid = threadIdx.x;
  for (int w = tid; w < 32 * Kn; w += 256)
    lidx[w] = idx[((size_t)b * Np + n0) * Kn + w];
  __syncthreads();
  int oo = tid % O;
  int ns0 = tid / O;
  int step = 256 / O;
  float acc = 0.f, acc2 = 0.f;
  for (int ns = ns0; ns < 32; ns += step) {
    float tv = t[((size_t)b * Np + n0 + ns) * O + oo];
    for (int k = 0; k < Kn; ++k) {
      int j = lidx[ns * Kn + k];
      float y = u[((size_t)b * srcNp + j) * O + oo] + tv;
      acc += y;
      acc2 += y * y;
    }
  }
  atomicAdd(&stats[oo], (double)acc);
  atomicAdd(&stats[O + oo], (double)acc2);
}

// ---------------- fold BN into per-channel scale/shift ----------------
__global__ void k_bnfin(const double* __restrict__ stats, const float* __restrict__ gamma,
                        const float* __restrict__ beta, float* __restrict__ sc,
                        int O, double cnt) {
  int o = threadIdx.x;
  if (o >= O) return;
  double mean = stats[o] / cnt;
  double var = stats[O + o] / cnt - mean * mean;
  if (var < 0.0) var = 0.0;
  double rstd = 1.0 / sqrt(var + 1e-5);
  float s = gamma[o] * (float)rstd;
  float c = beta[o] - (float)mean * s;
  sc[o] = s;
  sc[O + o] = c;
}

// ---------------- fused normalize + lrelu + max over K, write feature slice ----------------
__global__ __launch_bounds__(256) void k_edgemax(
    const float* __restrict__ u, const float* __restrict__ t, const int* __restrict__ idx,
    const float* __restrict__ sc, float* __restrict__ outf, int ldo, int coff,
    int O, int Np, int Kn, int srcNp) {
  __shared__ int lidx[32 * KNN];
  int b = blockIdx.y;
  int n0 = blockIdx.x * 32;
  int tid = threadIdx.x;
  for (int w = tid; w < 32 * Kn; w += 256)
    lidx[w] = idx[((size_t)b * Np + n0) * Kn + w];
  __syncthreads();
  for (int w = tid; w < 32 * O; w += 256) {
    int ns = w / O, oo = w % O;
    float s = sc[oo], c = sc[O + oo];
    float tv = t[((size_t)b * Np + n0 + ns) * O + oo];
    float best = -INFINITY;
    for (int k = 0; k < Kn; ++k) {
      int j = lidx[ns * Kn + k];
      float y = u[((size_t)b * srcNp + j) * O + oo] + tv;
      float a = s * y + c;
      a = (a >= 0.f) ? a : NEG_SLOPE * a;
      best = fmaxf(best, a);
    }
    outf[((size_t)b * Np + n0 + ns) * ldo + coff + oo] = best;
  }
}

// ------- layer 5 pass A: y = cat@w5^T tile, accumulate per-channel BN stats (no store) -------
__global__ __launch_bounds__(256) void k_mmstats(
    const float* __restrict__ src, const float* __restrict__ w,
    double* __restrict__ stats) {
  __shared__ float As[16][68];
  __shared__ float Ws[16][68];
  __shared__ float redS[16][64];
  __shared__ float redQ[16][64];
  int b = blockIdx.z;
  int j0 = blockIdx.y * 64;
  int o0 = blockIdx.x * 64;
  int tx = threadIdx.x, ty = threadIdx.y;
  int tid = ty * 16 + tx;
  const float* Sb = src + (size_t)b * NN * 512;
  float acc[4][4] = {};
  for (int c0 = 0; c0 < 512; c0 += 16) {
    for (int r = 0; r < 4; ++r) {
      int li = tid + r * 256;
      int row = li >> 4, k = li & 15;
      As[k][row] = Sb[(size_t)(j0 + row) * 512 + c0 + k];
      Ws[k][row] = w[(size_t)(o0 + row) * 512 + c0 + k];
    }
    __syncthreads();
#pragma unroll
    for (int k = 0; k < 16; ++k) {
      float a_[4], b_[4];
#pragma unroll
      for (int ii = 0; ii < 4; ++ii) a_[ii] = As[k][ty * 4 + ii];
#pragma unroll
      for (int jj = 0; jj < 4; ++jj) b_[jj] = Ws[k][tx * 4 + jj];
#pragma unroll
      for (int ii = 0; ii < 4; ++ii)
#pragma unroll
        for (int jj = 0; jj < 4; ++jj)
          acc[ii][jj] = fmaf(a_[ii], b_[jj], acc[ii][jj]);
    }
    __syncthreads();
  }
  for (int jj = 0; jj < 4; ++jj) {
    float s = 0.f, q = 0.f;
    for (int ii = 0; ii < 4; ++ii) { float v = acc[ii][jj]; s += v; q += v * v; }
    redS[ty][tx * 4 + jj] = s;
    redQ[ty][tx * 4 + jj] = q;
  }
  __syncthreads();
  if (tid < 64) {
    float s = 0.f, q = 0.f;
    for (int r = 0; r < 16; ++r) { s += redS[r][tid]; q += redQ[r][tid]; }
    atomicAdd(&stats[o0 + tid], (double)s);
    atomicAdd(&stats[512 + o0 + tid], (double)q);
  }
}

// ------- layer 5 pass B: recompute y tile, BN+lrelu, transposed f32 store -------
__global__ __launch_bounds__(256) void k_final5(
    const float* __restrict__ src, const float* __restrict__ w,
    const float* __restrict__ sc, float* __restrict__ out) {
  __shared__ float As[16][68];
  __shared__ float Ws[16][68];
  __shared__ float tile[64][65];
  int b = blockIdx.z;
  int j0 = blockIdx.y * 64;
  int o0 = blockIdx.x * 64;
  int tx = threadIdx.x, ty = threadIdx.y;
  int tid = ty * 16 + tx;
  const float* Sb = src + (size_t)b * NN * 512;
  float acc[4][4] = {};
  for (int c0 = 0; c0 < 512; c0 += 16) {
    for (int r = 0; r < 4; ++r) {
      int li = tid + r * 256;
      int row = li >> 4, k = li & 15;
      As[k][row] = Sb[(size_t)(j0 + row) * 512 + c0 + k];
      Ws[k][row] = w[(size_t)(o0 + row) * 512 + c0 + k];
    }
    __syncthreads();
#pragma unroll
    for (int k = 0; k < 16; ++k) {
      float a_[4], b_[4];
#pragma unroll
      for (int ii = 0; ii < 4; ++ii) a_[ii] = As[k][ty * 4 + ii];
#pragma unroll
      for (int jj = 0; jj < 4; ++jj) b_[jj] = Ws[k][tx * 4 + jj];
#pragma unroll
      for (int ii = 0; ii < 4; ++ii)
#pragma unroll
        for (int jj = 0; jj < 4; ++jj)
          acc[ii][jj] = fmaf(a_[ii], b_[jj], acc[ii][jj]);
    }
    __syncthreads();
  }
  for (int ii = 0; ii < 4; ++ii)
    for (int jj = 0; jj < 4; ++jj) {
      int nl = ty * 4 + ii, ol = tx * 4 + jj;
      float a = sc[o0 + ol] * acc[ii][jj] + sc[512 + o0 + ol];
      a = (a >= 0.f) ? a : NEG_SLOPE * a;
      tile[nl][ol] = a;
    }
  __syncthreads();
  for (int r = 0; r < 16; ++r) {
    int li = tid + r * 256;
    int ol = li >> 6, nl = li & 63;
    out[((size_t)b * 512 + o0 + ol) * NN + j0 + nl] = tile[nl][ol];
  }
}

// =====================================================================================
// f32 inputs/outputs (round-4 sniffer proved flag=0: rounds 1-3 NaN'd from bf16 misread).
// Distances in f64 to eliminate knn near-tie flips vs the np reference.
// Workspace: fixed ~21 MB + DD chunk CB*8MB, CB chosen from ws_size at runtime (>=1).
// uu (<=8 MB f32) lives in d_out (16 MB f32, dead before k_final5 writes).
extern "C" void kernel_launch(void* const* d_in, const int* in_sizes, int n_in,
                              void* d_out, int out_size, void* d_ws, size_t ws_size,
                              hipStream_t stream) {
  const float* x = (const float*)d_in[0];
  const float* y = (const float*)d_in[1];
  const float* w1 = (const float*)d_in[2];
  const float* w2 = (const float*)d_in[3];
  const float* w3 = (const float*)d_in[4];
  const float* w4 = (const float*)d_in[5];
  const float* w5 = (const float*)d_in[6];
  const float* g1 = (const float*)d_in[7];
  const float* b1 = (const float*)d_in[8];
  const float* g2 = (const float*)d_in[9];
  const float* b2 = (const float*)d_in[10];
  const float* g3 = (const float*)d_in[11];
  const float* b3 = (const float*)d_in[12];
  const float* g4 = (const float*)d_in[13];
  const float* b4 = (const float*)d_in[14];
  const float* g5 = (const float*)d_in[15];
  const float* b5 = (const float*)d_in[16];

  char* base = (char*)d_ws;
  size_t off = 0;
  auto alloc = [&](size_t bytes) -> char* {
    char* p = base + off;
    off += (bytes + 255) & ~(size_t)255;
    return p;
  };
  double* st = (double*)alloc(1024 * 8);
  float* sc  = (float*)alloc(1024 * 4);
  double* sq  = (double*)alloc((size_t)BB * NN * 8);
  double* rnx = (double*)alloc((size_t)BB * NN * 8);
  double* rny = (double*)alloc((size_t)BB * MM * 8);
  int*   idxb = (int*)alloc((size_t)BB * NN * KNN * 4);
  float* xs3 = (float*)alloc((size_t)BB * NN * 3 * 4);     // x transposed (B,N,3)
  float* ys  = (float*)alloc((size_t)BB * MM * 128 * 4);   // y transposed (B,M,128)
  float* cat = (float*)alloc((size_t)BB * NN * 512 * 4);   // x1|x2|x3|x4 (B,N,512)
  // adaptive DD chunk: CB batches of f64 NxM, unioned with tt (f32, <=8 MB)
  size_t ddBatchBytes = (size_t)NN * MM * 8;               // 8 MB per batch
  size_t avail = (ws_size > off) ? (ws_size - off) : 0;
  int CB = (int)(avail / ddBatchBytes);
  if (CB < 1) CB = 1;
  if (CB > BB) CB = BB;
  char*  U   = alloc((size_t)CB * ddBatchBytes);
  double* DD = (double*)U;                                 // dist/simi chunk (f64)
  float* tt  = (float*)U;                                  // center term (f32, <=8MB)
  float* uu  = (float*)d_out;                              // source term (<=8MB of 16MB)
  float* outp = (float*)d_out;

  const dim3 blk2(16, 16);
  const double cntE = (double)BB * NN * KNN;  // 163840

  auto knn = [&](const float* A, int lda, const float* Bm, int ldb,
                 const double* sa, const double* sb, int C, int mode) {
    for (int b0 = 0; b0 < BB; b0 += CB) {
      int cb = (BB - b0 < CB) ? (BB - b0) : CB;
      dim3 g(MM / 64, NN / 64, cb);
      if (mode == 1) k_gram<1><<<g, blk2, 0, stream>>>(A, lda, Bm, ldb, sa, sb, DD, C, b0);
      else           k_gram<2><<<g, blk2, 0, stream>>>(A, lda, Bm, ldb, sa, sb, DD, C, b0);
      k_topk<<<cb * 256, 256, 0, stream>>>(DD, idxb, b0);
    }
  };

  // ---- input transposes ----
  k_transpose<<<96, 256, 0, stream>>>(x, xs3, 3, NN);
  k_transpose<<<2048, 256, 0, stream>>>(y, ys, 128, MM);

  // ---- layer 1: C=3, O=64, w1 (64,6) ----
  k_rowsq<0><<<32, 256, 0, stream>>>(xs3, 3, 3, sq);
  knn(xs3, 3, xs3, 3, sq, sq, 3, 1);
  k_featmm<<<dim3(1, 16, 8), blk2, 0, stream>>>(xs3, 3, w1, 6, uu, 3, 64, 0, NN);
  k_featmm<<<dim3(1, 16, 8), blk2, 0, stream>>>(xs3, 3, w1, 6, tt, 3, 64, 1, NN);
  hipMemsetAsync(st, 0, 1024 * 8, stream);
  k_bnstats<<<dim3(32, 8), 256, 0, stream>>>(uu, tt, idxb, st, 64, NN, KNN, MM);
  k_bnfin<<<1, 64, 0, stream>>>(st, g1, b1, sc, 64, cntE);
  k_edgemax<<<dim3(32, 8), 256, 0, stream>>>(uu, tt, idxb, sc, cat, 512, 0, 64, NN, KNN, MM);

  // ---- layer 2: input x1 = cat[:,0:64], C=64, O=64, w2 (64,128) ----
  k_rowsq<0><<<32, 256, 0, stream>>>(cat, 512, 64, sq);
  knn(cat, 512, cat, 512, sq, sq, 64, 1);
  k_featmm<<<dim3(1, 16, 8), blk2, 0, stream>>>(cat, 512, w2, 128, uu, 64, 64, 0, NN);
  k_featmm<<<dim3(1, 16, 8), blk2, 0, stream>>>(cat, 512, w2, 128, tt, 64, 64, 1, NN);
  hipMemsetAsync(st, 0, 1024 * 8, stream);
  k_bnstats<<<dim3(32, 8), 256, 0, stream>>>(uu, tt, idxb, st, 64, NN, KNN, MM);
  k_bnfin<<<1, 64, 0, stream>>>(st, g2, b2, sc, 64, cntE);
  k_edgemax<<<dim3(32, 8), 256, 0, stream>>>(uu, tt, idxb, sc, cat, 512, 64, 64, NN, KNN, MM);

  // ---- layer 3: input x2 = cat[:,64:128], C=64, O=128, w3 (128,128) ----
  k_rowsq<0><<<32, 256, 0, stream>>>(cat + 64, 512, 64, sq);
  knn(cat + 64, 512, cat + 64, 512, sq, sq, 64, 1);
  k_featmm<<<dim3(2, 16, 8), blk2, 0, stream>>>(cat + 64, 512, w3, 128, uu, 64, 128, 0, NN);
  k_featmm<<<dim3(2, 16, 8), blk2, 0, stream>>>(cat + 64, 512, w3, 128, tt, 64, 128, 1, NN);
  hipMemsetAsync(st, 0, 1024 * 8, stream);
  k_bnstats<<<dim3(32, 8), 256, 0, stream>>>(uu, tt, idxb, st, 128, NN, KNN, MM);
  k_bnfin<<<1, 128, 0, stream>>>(st, g3, b3, sc, 128, cntE);
  k_edgemax<<<dim3(32, 8), 256, 0, stream>>>(uu, tt, idxb, sc, cat, 512, 128, 128, NN, KNN, MM);

  // ---- layer 4 (IA): x3 = cat[:,128:256] (C=128), src = y; cosine knn; O=256, w4 (256,256) ----
  k_rowsq<1><<<32, 256, 0, stream>>>(cat + 128, 512, 128, rnx);
  k_rowsq<1><<<32, 256, 0, stream>>>(ys, 128, 128, rny);
  knn(cat + 128, 512, ys, 128, rnx, rny, 128, 2);
  k_featmm<<<dim3(4, 16, 8), blk2, 0, stream>>>(ys, 128, w4, 256, uu, 128, 256, 0, MM);
  k_featmm<<<dim3(4, 16, 8), blk2, 0, stream>>>(cat + 128, 512, w4, 256, tt, 128, 256, 1, NN);
  hipMemsetAsync(st, 0, 1024 * 8, stream);
  k_bnstats<<<dim3(32, 8), 256, 0, stream>>>(uu, tt, idxb, st, 256, NN, KNN, MM);
  k_bnfin<<<1, 256, 0, stream>>>(st, g4, b4, sc, 256, cntE);
  k_edgemax<<<dim3(32, 8), 256, 0, stream>>>(uu, tt, idxb, sc, cat, 512, 256, 256, NN, KNN, MM);

  // ---- layer 5: recompute-two-pass GEMM (C=512,O=512), BN over (B,N), lrelu, out ----
  hipMemsetAsync(st, 0, 1024 * 8, stream);
  k_mmstats<<<dim3(8, 16, 8), blk2, 0, stream>>>(cat, w5, st);
  k_bnfin<<<1, 512, 0, stream>>>(st, g5, b5, sc, 512, (double)(BB * NN));
  k_final5<<<dim3(8, 16, 8), blk2, 0, stream>>>(cat, w5, sc, outp);
}

// Round 6
// 888.523 us; speedup vs baseline: 1.2954x; 1.2954x over previous
//
#include <hip/hip_runtime.h>
#include <hip/hip_bf16.h>

#define KNN 20
#define NEG_SLOPE 0.2f

constexpr int BB = 8;
constexpr int NN = 1024;
constexpr int MM = 1024;

// ---------------- transpose f32: (B,C,Np) -> (B,Np,C) ----------------
__global__ __launch_bounds__(256) void k_transpose(
    const float* __restrict__ in, float* __restrict__ out, int C, int Np) {
  int total = BB * C * Np;
  for (int t = blockIdx.x * 256 + threadIdx.x; t < total; t += gridDim.x * 256) {
    int c = t % C;
    int n = (t / C) % Np;
    int b = t / (C * Np);
    out[t] = in[((size_t)b * C + c) * Np + n];
  }
}

// ------- per-point squared norm (RECIP=0) or reciprocal norm (RECIP=1), f64 out -------
template <int RECIP>
__global__ __launch_bounds__(256) void k_rowsq(
    const float* __restrict__ A, int ld, int C, double* __restrict__ sq) {
  int p = blockIdx.x * 256 + threadIdx.x;
  if (p >= BB * NN) return;
  const float* row = A + (size_t)p * ld;
  double s = 0.0;
  for (int c = 0; c < C; ++c) { double v = (double)row[c]; s += v * v; }
  if (RECIP) {
    sq[p] = 1.0 / fmax(sqrt(s), 1e-12);
  } else {
    sq[p] = s;
  }
}

// ---------------- batched gram over a CB-batch chunk starting at b0, f64 ----------------
// MODE 1: D = 2*dot - sqA_i - sqB_j   (euclidean knn)
// MODE 2: D = dot * rnA_i * rnB_j     (cosine; sqA/sqB hold reciprocal norms)
template <int MODE>
__global__ __launch_bounds__(256) void k_gram(
    const float* __restrict__ A, int lda, const float* __restrict__ Bm, int ldb,
    const double* __restrict__ sqA, const double* __restrict__ sqB,
    double* __restrict__ D, int C, int b0) {
  __shared__ float As[16][68];
  __shared__ float Bs[16][68];
  int bg = b0 + blockIdx.z;
  int bl = blockIdx.z;
  int i0 = blockIdx.y * 64;
  int j0 = blockIdx.x * 64;
  const float* Ab = A + (size_t)bg * NN * lda;
  const float* Bb = Bm + (size_t)bg * MM * ldb;
  int tx = threadIdx.x, ty = threadIdx.y;
  int tid = ty * 16 + tx;
  double acc[4][4] = {};
  for (int c0 = 0; c0 < C; c0 += 16) {
    for (int r = 0; r < 4; ++r) {
      int li = tid + r * 256;
      int row = li >> 4, k = li & 15;
      int c = c0 + k;
      As[k][row] = (c < C) ? Ab[(size_t)(i0 + row) * lda + c] : 0.f;
      Bs[k][row] = (c < C) ? Bb[(size_t)(j0 + row) * ldb + c] : 0.f;
    }
    __syncthreads();
#pragma unroll
    for (int k = 0; k < 16; ++k) {
      double a_[4], b_[4];
#pragma unroll
      for (int ii = 0; ii < 4; ++ii) a_[ii] = (double)As[k][ty * 4 + ii];
#pragma unroll
      for (int jj = 0; jj < 4; ++jj) b_[jj] = (double)Bs[k][tx * 4 + jj];
#pragma unroll
      for (int ii = 0; ii < 4; ++ii)
#pragma unroll
        for (int jj = 0; jj < 4; ++jj)
          acc[ii][jj] = fma(a_[ii], b_[jj], acc[ii][jj]);
    }
    __syncthreads();
  }
  for (int ii = 0; ii < 4; ++ii) {
    int i = i0 + ty * 4 + ii;
    for (int jj = 0; jj < 4; ++jj) {
      int j = j0 + tx * 4 + jj;
      double r = acc[ii][jj];
      if (MODE == 1) r = 2.0 * r - sqA[bg * NN + i] - sqB[bg * NN + j];
      if (MODE == 2) r = r * sqA[bg * NN + i] * sqB[bg * NN + j];
      D[((size_t)bl * NN + i) * MM + j] = r;
    }
  }
}

// ------- top-20 per row over the chunk, f64 (largest value, tie -> lowest index) -------
__global__ __launch_bounds__(256) void k_topk(const double* __restrict__ D,
                                              int* __restrict__ idx, int b0) {
  int wave = threadIdx.x >> 6;
  int lane = threadIdx.x & 63;
  int p = blockIdx.x * 4 + wave;
  const double* row = D + (size_t)p * MM;
  double v[16];
#pragma unroll
  for (int m = 0; m < 16; ++m) v[m] = row[m * 64 + lane];
  int* op = idx + ((size_t)b0 * NN + p) * KNN;
  for (int r = 0; r < KNN; ++r) {
    double bv = -INFINITY;
    int bj = MM;
#pragma unroll
    for (int m = 0; m < 16; ++m) {
      if (v[m] > bv) { bv = v[m]; bj = m * 64 + lane; }
    }
#pragma unroll
    for (int off = 32; off > 0; off >>= 1) {
      double ov = __shfl_xor(bv, off, 64);
      int oj = __shfl_xor(bj, off, 64);
      if (ov > bv || (ov == bv && oj < bj)) { bv = ov; bj = oj; }
    }
    if (bj < MM && lane == (bj & 63)) v[bj >> 6] = -INFINITY;
    if (lane == 0) op[r] = bj;
  }
}

// ------- per-point feature matmul: out[b,j,o] = sum_c src[b,j,c] * weff[o,c] (f32) -------
// mode 0: weff = w[o,c]; mode 1: weff = w[o,C+c] - w[o,c]
__global__ __launch_bounds__(256) void k_featmm(
    const float* __restrict__ src, int lds_, const float* __restrict__ w, int CW,
    float* __restrict__ out, int C, int O, int mode, int Np) {
  __shared__ float As[16][68];
  __shared__ float Ws[16][68];
  int b = blockIdx.z;
  int j0 = blockIdx.y * 64;
  int o0 = blockIdx.x * 64;
  int tx = threadIdx.x, ty = threadIdx.y;
  int tid = ty * 16 + tx;
  const float* Sb = src + (size_t)b * Np * lds_;
  float acc[4][4] = {};
  for (int c0 = 0; c0 < C; c0 += 16) {
    for (int r = 0; r < 4; ++r) {
      int li = tid + r * 256;
      int row = li >> 4, k = li & 15;
      int c = c0 + k;
      As[k][row] = (c < C) ? Sb[(size_t)(j0 + row) * lds_ + c] : 0.f;
      float wv = 0.f;
      if (c < C) {
        const float* wr = w + (size_t)(o0 + row) * CW;
        wv = mode == 0 ? wr[c] : (wr[C + c] - wr[c]);
      }
      Ws[k][row] = wv;
    }
    __syncthreads();
#pragma unroll
    for (int k = 0; k < 16; ++k) {
      float a_[4], b_[4];
#pragma unroll
      for (int ii = 0; ii < 4; ++ii) a_[ii] = As[k][ty * 4 + ii];
#pragma unroll
      for (int jj = 0; jj < 4; ++jj) b_[jj] = Ws[k][tx * 4 + jj];
#pragma unroll
      for (int ii = 0; ii < 4; ++ii)
#pragma unroll
        for (int jj = 0; jj < 4; ++jj)
          acc[ii][jj] = fmaf(a_[ii], b_[jj], acc[ii][jj]);
    }
    __syncthreads();
  }
  for (int ii = 0; ii < 4; ++ii) {
    int j = j0 + ty * 4 + ii;
    float4 v;
    float* vp = &v.x;
    for (int jj = 0; jj < 4; ++jj) vp[jj] = acc[ii][jj];
    *(float4*)&out[((size_t)b * Np + j) * O + o0 + tx * 4] = v;
  }
}

// ------- fused gather: per (n,o) compute max_k y (y = u[idx]+t), accumulate BN stats -------
// grid: (NN/16, B, O/64), 256 threads = 64 channels x 4 point-slots
__global__ __launch_bounds__(256) void k_gather(
    const float* __restrict__ u, const float* __restrict__ t, const int* __restrict__ idx,
    double* __restrict__ stats, float* __restrict__ mx, int O, int srcNp) {
  __shared__ int lidx[16 * KNN];
  __shared__ double rs[256];
  __shared__ double rq[256];
  int b = blockIdx.y;
  int n0 = blockIdx.x * 16;
  int o0 = blockIdx.z * 64;
  int tid = threadIdx.x;
  int lane = tid & 63, nsl = tid >> 6;
  for (int w = tid; w < 16 * KNN; w += 256)
    lidx[w] = idx[((size_t)b * NN + n0) * KNN + w];
  __syncthreads();
  int oo = o0 + lane;
  double s1 = 0.0, s2 = 0.0;
  for (int ns = nsl; ns < 16; ns += 4) {
    size_t row = (size_t)b * NN + n0 + ns;
    float tv = t[row * O + oo];
    float mxv = -INFINITY, a1 = 0.f, a2 = 0.f;
#pragma unroll
    for (int k = 0; k < KNN; ++k) {
      int j = lidx[ns * KNN + k];
      float yv = u[((size_t)b * srcNp + j) * O + oo] + tv;
      mxv = fmaxf(mxv, yv);
      a1 += yv;
      a2 = fmaf(yv, yv, a2);
    }
    mx[row * O + oo] = mxv;
    s1 += (double)a1;
    s2 += (double)a2;
  }
  rs[tid] = s1;
  rq[tid] = s2;
  __syncthreads();
  if (tid < 64) {
    s1 = rs[tid] + rs[tid + 64] + rs[tid + 128] + rs[tid + 192];
    s2 = rq[tid] + rq[tid + 64] + rq[tid + 128] + rq[tid + 192];
    atomicAdd(&stats[o0 + tid], s1);
    atomicAdd(&stats[O + o0 + tid], s2);
  }
}

// ---------------- fold BN into per-channel scale/shift ----------------
__global__ void k_bnfin(const double* __restrict__ stats, const float* __restrict__ gamma,
                        const float* __restrict__ beta, float* __restrict__ sc,
                        int O, double cnt) {
  int o = threadIdx.x;
  if (o >= O) return;
  double mean = stats[o] / cnt;
  double var = stats[O + o] / cnt - mean * mean;
  if (var < 0.0) var = 0.0;
  double rstd = 1.0 / sqrt(var + 1e-5);
  float s = gamma[o] * (float)rstd;
  float c = beta[o] - (float)mean * s;
  sc[o] = s;
  sc[O + o] = c;
}

// ------- apply BN+lrelu to stored max, write cat slice. s<0 fallback: re-gather min -------
__global__ __launch_bounds__(256) void k_bnapply(
    const float* __restrict__ mx, const float* __restrict__ u, const float* __restrict__ t,
    const int* __restrict__ idx, const float* __restrict__ sc, float* __restrict__ cat,
    int coff, int O, int srcNp) {
  int i = blockIdx.x * 256 + threadIdx.x;
  int total = BB * NN * O;
  if (i >= total) return;
  int oo = i % O;
  int n = (i / O) % NN;
  int b = i / (O * NN);
  float s = sc[oo], c = sc[O + oo];
  float v;
  if (s >= 0.f) {
    v = mx[i];
  } else {  // monotone-decreasing transform: need min_k y (never hit with gamma=1)
    float tv = t[i];
    float mn = INFINITY;
    for (int k = 0; k < KNN; ++k) {
      int j = idx[((size_t)b * NN + n) * KNN + k];
      mn = fminf(mn, u[((size_t)b * srcNp + j) * O + oo] + tv);
    }
    v = mn;
  }
  float a = s * v + c;
  a = (a >= 0.f) ? a : NEG_SLOPE * a;
  cat[((size_t)b * NN + n) * 512 + coff + oo] = a;
}

// ------- layer 5 pass A: y = cat@w5^T tile, accumulate per-channel BN stats (no store) -------
__global__ __launch_bounds__(256) void k_mmstats(
    const float* __restrict__ src, const float* __restrict__ w,
    double* __restrict__ stats) {
  __shared__ float As[16][68];
  __shared__ float Ws[16][68];
  __shared__ float redS[16][64];
  __shared__ float redQ[16][64];
  int b = blockIdx.z;
  int j0 = blockIdx.y * 64;
  int o0 = blockIdx.x * 64;
  int tx = threadIdx.x, ty = threadIdx.y;
  int tid = ty * 16 + tx;
  const float* Sb = src + (size_t)b * NN * 512;
  float acc[4][4] = {};
  for (int c0 = 0; c0 < 512; c0 += 16) {
    for (int r = 0; r < 4; ++r) {
      int li = tid + r * 256;
      int row = li >> 4, k = li & 15;
      As[k][row] = Sb[(size_t)(j0 + row) * 512 + c0 + k];
      Ws[k][row] = w[(size_t)(o0 + row) * 512 + c0 + k];
    }
    __syncthreads();
#pragma unroll
    for (int k = 0; k < 16; ++k) {
      float a_[4], b_[4];
#pragma unroll
      for (int ii = 0; ii < 4; ++ii) a_[ii] = As[k][ty * 4 + ii];
#pragma unroll
      for (int jj = 0; jj < 4; ++jj) b_[jj] = Ws[k][tx * 4 + jj];
#pragma unroll
      for (int ii = 0; ii < 4; ++ii)
#pragma unroll
        for (int jj = 0; jj < 4; ++jj)
          acc[ii][jj] = fmaf(a_[ii], b_[jj], acc[ii][jj]);
    }
    __syncthreads();
  }
  for (int jj = 0; jj < 4; ++jj) {
    float s = 0.f, q = 0.f;
    for (int ii = 0; ii < 4; ++ii) { float v = acc[ii][jj]; s += v; q += v * v; }
    redS[ty][tx * 4 + jj] = s;
    redQ[ty][tx * 4 + jj] = q;
  }
  __syncthreads();
  if (tid < 64) {
    float s = 0.f, q = 0.f;
    for (int r = 0; r < 16; ++r) { s += redS[r][tid]; q += redQ[r][tid]; }
    atomicAdd(&stats[o0 + tid], (double)s);
    atomicAdd(&stats[512 + o0 + tid], (double)q);
  }
}

// ------- layer 5 pass B: recompute y tile, BN+lrelu, transposed f32 store -------
__global__ __launch_bounds__(256) void k_final5(
    const float* __restrict__ src, const float* __restrict__ w,
    const float* __restrict__ sc, float* __restrict__ out) {
  __shared__ float As[16][68];
  __shared__ float Ws[16][68];
  __shared__ float tile[64][65];
  int b = blockIdx.z;
  int j0 = blockIdx.y * 64;
  int o0 = blockIdx.x * 64;
  int tx = threadIdx.x, ty = threadIdx.y;
  int tid = ty * 16 + tx;
  const float* Sb = src + (size_t)b * NN * 512;
  float acc[4][4] = {};
  for (int c0 = 0; c0 < 512; c0 += 16) {
    for (int r = 0; r < 4; ++r) {
      int li = tid + r * 256;
      int row = li >> 4, k = li & 15;
      As[k][row] = Sb[(size_t)(j0 + row) * 512 + c0 + k];
      Ws[k][row] = w[(size_t)(o0 + row) * 512 + c0 + k];
    }
    __syncthreads();
#pragma unroll
    for (int k = 0; k < 16; ++k) {
      float a_[4], b_[4];
#pragma unroll
      for (int ii = 0; ii < 4; ++ii) a_[ii] = As[k][ty * 4 + ii];
#pragma unroll
      for (int jj = 0; jj < 4; ++jj) b_[jj] = Ws[k][tx * 4 + jj];
#pragma unroll
      for (int ii = 0; ii < 4; ++ii)
#pragma unroll
        for (int jj = 0; jj < 4; ++jj)
          acc[ii][jj] = fmaf(a_[ii], b_[jj], acc[ii][jj]);
    }
    __syncthreads();
  }
  for (int ii = 0; ii < 4; ++ii)
    for (int jj = 0; jj < 4; ++jj) {
      int nl = ty * 4 + ii, ol = tx * 4 + jj;
      float a = sc[o0 + ol] * acc[ii][jj] + sc[512 + o0 + ol];
      a = (a >= 0.f) ? a : NEG_SLOPE * a;
      tile[nl][ol] = a;
    }
  __syncthreads();
  for (int r = 0; r < 16; ++r) {
    int li = tid + r * 256;
    int ol = li >> 6, nl = li & 63;
    out[((size_t)b * 512 + o0 + ol) * NN + j0 + nl] = tile[nl][ol];
  }
}

// =====================================================================================
// f32 in/out. f64 distances (knn tie-exactness vs np ref). Single fused gather per layer
// (max-trick: BN+lrelu monotone for s>=0; s<0 handled by re-gather fallback in k_bnapply).
// d_out (16MB): uu [0:8MB] | mx [8:16MB], both dead before k_final5 writes.
// ws: fixed ~21.2MB + U (max(CB,1)*8MB; DD chunk, dead after topk, reused as tt).
extern "C" void kernel_launch(void* const* d_in, const int* in_sizes, int n_in,
                              void* d_out, int out_size, void* d_ws, size_t ws_size,
                              hipStream_t stream) {
  const float* x = (const float*)d_in[0];
  const float* y = (const float*)d_in[1];
  const float* w1 = (const float*)d_in[2];
  const float* w2 = (const float*)d_in[3];
  const float* w3 = (const float*)d_in[4];
  const float* w4 = (const float*)d_in[5];
  const float* w5 = (const float*)d_in[6];
  const float* g1 = (const float*)d_in[7];
  const float* b1 = (const float*)d_in[8];
  const float* g2 = (const float*)d_in[9];
  const float* b2 = (const float*)d_in[10];
  const float* g3 = (const float*)d_in[11];
  const float* b3 = (const float*)d_in[12];
  const float* g4 = (const float*)d_in[13];
  const float* b4 = (const float*)d_in[14];
  const float* g5 = (const float*)d_in[15];
  const float* b5 = (const float*)d_in[16];

  char* base = (char*)d_ws;
  size_t off = 0;
  auto alloc = [&](size_t bytes) -> char* {
    char* p = base + off;
    off += (bytes + 255) & ~(size_t)255;
    return p;
  };
  double* st = (double*)alloc(1024 * 8);
  float* sc  = (float*)alloc(1024 * 4);
  double* sq  = (double*)alloc((size_t)BB * NN * 8);
  double* rnx = (double*)alloc((size_t)BB * NN * 8);
  double* rny = (double*)alloc((size_t)BB * MM * 8);
  int*   idxb = (int*)alloc((size_t)BB * NN * KNN * 4);
  float* xs3 = (float*)alloc((size_t)BB * NN * 3 * 4);
  float* ys  = (float*)alloc((size_t)BB * MM * 128 * 4);
  float* cat = (float*)alloc((size_t)BB * NN * 512 * 4);
  size_t ddBatchBytes = (size_t)NN * MM * 8;  // 8 MB per batch (f64)
  size_t avail = (ws_size > off) ? (ws_size - off) : 0;
  int CB = (int)(avail / ddBatchBytes);
  if (CB < 1) CB = 1;
  if (CB > BB) CB = BB;
  char*  U   = alloc((size_t)CB * ddBatchBytes);
  double* DD = (double*)U;                     // dist/simi chunk (f64), dead after topk
  float* tt  = (float*)U;                      // center term (f32, <=8MB), after DD dead
  float* uu  = (float*)d_out;                  // source term (<=8MB)
  float* mx  = (float*)d_out + (size_t)2 * 1024 * 1024;  // max_k y (<=8MB)
  float* outp = (float*)d_out;

  const dim3 blk2(16, 16);
  const double cntE = (double)BB * NN * KNN;

  auto knn = [&](const float* A, int lda, const float* Bm, int ldb,
                 const double* sa, const double* sb, int C, int mode) {
    for (int b0 = 0; b0 < BB; b0 += CB) {
      int cb = (BB - b0 < CB) ? (BB - b0) : CB;
      dim3 g(MM / 64, NN / 64, cb);
      if (mode == 1) k_gram<1><<<g, blk2, 0, stream>>>(A, lda, Bm, ldb, sa, sb, DD, C, b0);
      else           k_gram<2><<<g, blk2, 0, stream>>>(A, lda, Bm, ldb, sa, sb, DD, C, b0);
      k_topk<<<cb * 256, 256, 0, stream>>>(DD, idxb, b0);
    }
  };

  auto edge_layer = [&](const float* ctr, int ldc, const float* src, int ldsrc, int srcNp,
                        const float* w, int CW, const float* g, const float* bb,
                        int C, int O, int coff) {
    k_featmm<<<dim3(O / 64, 16, 8), blk2, 0, stream>>>(src, ldsrc, w, CW, uu, C, O, 0, srcNp);
    k_featmm<<<dim3(O / 64, 16, 8), blk2, 0, stream>>>(ctr, ldc, w, CW, tt, C, O, 1, NN);
    hipMemsetAsync(st, 0, 1024 * 8, stream);
    k_gather<<<dim3(NN / 16, BB, O / 64), 256, 0, stream>>>(uu, tt, idxb, st, mx, O, srcNp);
    k_bnfin<<<1, O, 0, stream>>>(st, g, bb, sc, O, cntE);
    k_bnapply<<<(BB * NN * O + 255) / 256, 256, 0, stream>>>(mx, uu, tt, idxb, sc, cat,
                                                             coff, O, srcNp);
  };

  // ---- input transposes ----
  k_transpose<<<96, 256, 0, stream>>>(x, xs3, 3, NN);
  k_transpose<<<2048, 256, 0, stream>>>(y, ys, 128, MM);

  // ---- layer 1: C=3, O=64 ----
  k_rowsq<0><<<32, 256, 0, stream>>>(xs3, 3, 3, sq);
  knn(xs3, 3, xs3, 3, sq, sq, 3, 1);
  edge_layer(xs3, 3, xs3, 3, NN, w1, 6, g1, b1, 3, 64, 0);

  // ---- layer 2: x1 = cat[:,0:64], C=64, O=64 ----
  k_rowsq<0><<<32, 256, 0, stream>>>(cat, 512, 64, sq);
  knn(cat, 512, cat, 512, sq, sq, 64, 1);
  edge_layer(cat, 512, cat, 512, NN, w2, 128, g2, b2, 64, 64, 64);

  // ---- layer 3: x2 = cat[:,64:128], C=64, O=128 ----
  k_rowsq<0><<<32, 256, 0, stream>>>(cat + 64, 512, 64, sq);
  knn(cat + 64, 512, cat + 64, 512, sq, sq, 64, 1);
  edge_layer(cat + 64, 512, cat + 64, 512, NN, w3, 128, g3, b3, 64, 128, 128);

  // ---- layer 4 (IA): x3 = cat[:,128:256], src = y (cosine knn), C=128, O=256 ----
  k_rowsq<1><<<32, 256, 0, stream>>>(cat + 128, 512, 128, rnx);
  k_rowsq<1><<<32, 256, 0, stream>>>(ys, 128, 128, rny);
  knn(cat + 128, 512, ys, 128, rnx, rny, 128, 2);
  edge_layer(cat + 128, 512, ys, 128, MM, w4, 256, g4, b4, 128, 256, 256);

  // ---- layer 5: recompute-two-pass GEMM (C=512,O=512), BN over (B,N), lrelu, out ----
  hipMemsetAsync(st, 0, 1024 * 8, stream);
  k_mmstats<<<dim3(8, 16, 8), blk2, 0, stream>>>(cat, w5, st);
  k_bnfin<<<1, 512, 0, stream>>>(st, g5, b5, sc, 512, (double)(BB * NN));
  k_final5<<<dim3(8, 16, 8), blk2, 0, stream>>>(cat, w5, sc, outp);
}

// Round 7
// 842.663 us; speedup vs baseline: 1.3659x; 1.0544x over previous
//
#include <hip/hip_runtime.h>
#include <hip/hip_bf16.h>

#define KNN 20
#define NEG_SLOPE 0.2f

constexpr int BB = 8;
constexpr int NN = 1024;
constexpr int MM = 1024;

// ---------------- transpose f32: (B,C,Np) -> (B,Np,C) ----------------
__global__ __launch_bounds__(256) void k_transpose(
    const float* __restrict__ in, float* __restrict__ out, int C, int Np) {
  int total = BB * C * Np;
  for (int t = blockIdx.x * 256 + threadIdx.x; t < total; t += gridDim.x * 256) {
    int c = t % C;
    int n = (t / C) % Np;
    int b = t / (C * Np);
    out[t] = in[((size_t)b * C + c) * Np + n];
  }
}

// ------- per-point squared norm (RECIP=0) or reciprocal norm (RECIP=1), f64 out -------
template <int RECIP>
__global__ __launch_bounds__(256) void k_rowsq(
    const float* __restrict__ A, int ld, int C, double* __restrict__ sq) {
  int p = blockIdx.x * 256 + threadIdx.x;
  if (p >= BB * NN) return;
  const float* row = A + (size_t)p * ld;
  double s = 0.0;
  for (int c = 0; c < C; ++c) { double v = (double)row[c]; s += v * v; }
  if (RECIP) {
    sq[p] = 1.0 / fmax(sqrt(s), 1e-12);
  } else {
    sq[p] = s;
  }
}

// ---------------- general gram (f64 LDS staging), CB-batch chunk from b0 ----------------
// MODE 1: D = 2*dot - sqA_i - sqB_j ; MODE 2: D = dot * rnA_i * rnB_j
template <int MODE>
__global__ __launch_bounds__(256) void k_gram(
    const float* __restrict__ A, int lda, const float* __restrict__ Bm, int ldb,
    const double* __restrict__ sqA, const double* __restrict__ sqB,
    double* __restrict__ D, int C, int b0) {
  __shared__ double As[16][68];
  __shared__ double Bs[16][68];
  int bg = b0 + blockIdx.z;
  int bl = blockIdx.z;
  int i0 = blockIdx.y * 64;
  int j0 = blockIdx.x * 64;
  const float* Ab = A + (size_t)bg * NN * lda;
  const float* Bb = Bm + (size_t)bg * MM * ldb;
  int tx = threadIdx.x, ty = threadIdx.y;
  int tid = ty * 16 + tx;
  double acc[4][4] = {};
  for (int c0 = 0; c0 < C; c0 += 16) {
    for (int r = 0; r < 4; ++r) {
      int li = tid + r * 256;
      int row = li >> 4, k = li & 15;
      int c = c0 + k;
      As[k][row] = (c < C) ? (double)Ab[(size_t)(i0 + row) * lda + c] : 0.0;
      Bs[k][row] = (c < C) ? (double)Bb[(size_t)(j0 + row) * ldb + c] : 0.0;
    }
    __syncthreads();
#pragma unroll
    for (int k = 0; k < 16; ++k) {
      double a_[4], b_[4];
#pragma unroll
      for (int ii = 0; ii < 4; ++ii) a_[ii] = As[k][ty * 4 + ii];
#pragma unroll
      for (int jj = 0; jj < 4; ++jj) b_[jj] = Bs[k][tx * 4 + jj];
#pragma unroll
      for (int ii = 0; ii < 4; ++ii)
#pragma unroll
        for (int jj = 0; jj < 4; ++jj)
          acc[ii][jj] = fma(a_[ii], b_[jj], acc[ii][jj]);
    }
    __syncthreads();
  }
  for (int ii = 0; ii < 4; ++ii) {
    int i = i0 + ty * 4 + ii;
    for (int jj = 0; jj < 4; ++jj) {
      int j = j0 + tx * 4 + jj;
      double r = acc[ii][jj];
      if (MODE == 1) r = 2.0 * r - sqA[bg * NN + i] - sqB[bg * NN + j];
      if (MODE == 2) r = r * sqA[bg * NN + i] * sqB[bg * NN + j];
      D[((size_t)bl * NN + i) * MM + j] = r;
    }
  }
}

// ------- symmetric euclidean gram (A==B): triangular block grid + mirrored write -------
__global__ __launch_bounds__(256) void k_gram_sym(
    const float* __restrict__ A, int lda, const double* __restrict__ sqA,
    double* __restrict__ D, int C, int b0) {
  __shared__ double As[16][68];
  __shared__ double Bs[16][68];
  __shared__ double T[64][65];
  int p = blockIdx.x;  // 0..135 triangular pair index (16x16 block grid, lower tri)
  int r = (int)((sqrtf(8.f * p + 1.f) - 1.f) * 0.5f);
  while ((r + 1) * (r + 2) / 2 <= p) ++r;
  while (r * (r + 1) / 2 > p) --r;
  int cc = p - r * (r + 1) / 2;
  int i0 = r * 64, j0 = cc * 64;
  int bg = b0 + blockIdx.z;
  int bl = blockIdx.z;
  const float* Ab = A + (size_t)bg * NN * lda;
  int tx = threadIdx.x, ty = threadIdx.y;
  int tid = ty * 16 + tx;
  double acc[4][4] = {};
  for (int c0 = 0; c0 < C; c0 += 16) {
    for (int rr = 0; rr < 4; ++rr) {
      int li = tid + rr * 256;
      int row = li >> 4, k = li & 15;
      int c = c0 + k;
      As[k][row] = (c < C) ? (double)Ab[(size_t)(i0 + row) * lda + c] : 0.0;
      Bs[k][row] = (c < C) ? (double)Ab[(size_t)(j0 + row) * lda + c] : 0.0;
    }
    __syncthreads();
#pragma unroll
    for (int k = 0; k < 16; ++k) {
      double a_[4], b_[4];
#pragma unroll
      for (int ii = 0; ii < 4; ++ii) a_[ii] = As[k][ty * 4 + ii];
#pragma unroll
      for (int jj = 0; jj < 4; ++jj) b_[jj] = Bs[k][tx * 4 + jj];
#pragma unroll
      for (int ii = 0; ii < 4; ++ii)
#pragma unroll
        for (int jj = 0; jj < 4; ++jj)
          acc[ii][jj] = fma(a_[ii], b_[jj], acc[ii][jj]);
    }
    __syncthreads();
  }
  // epilogue + direct write D[i][j]; stash transposed copy in T for the mirror
  for (int ii = 0; ii < 4; ++ii) {
    int i = i0 + ty * 4 + ii;
    for (int jj = 0; jj < 4; ++jj) {
      int j = j0 + tx * 4 + jj;
      double v = 2.0 * acc[ii][jj] - sqA[bg * NN + i] - sqA[bg * NN + j];
      D[((size_t)bl * NN + i) * MM + j] = v;
      T[tx * 4 + jj][ty * 4 + ii] = v;
    }
  }
  if (i0 != j0) {
    __syncthreads();
    for (int rr = 0; rr < 16; ++rr) {
      int li = tid + rr * 256;
      int jrow = li >> 6, il = li & 63;
      D[((size_t)bl * NN + j0 + jrow) * MM + i0 + il] = T[jrow][il];
    }
  }
}

// ------- top-20 per row over the chunk, f64 (largest value, tie -> lowest index) -------
__global__ __launch_bounds__(256) void k_topk(const double* __restrict__ D,
                                              int* __restrict__ idx, int b0) {
  int wave = threadIdx.x >> 6;
  int lane = threadIdx.x & 63;
  int p = blockIdx.x * 4 + wave;
  const double* row = D + (size_t)p * MM;
  double v[16];
#pragma unroll
  for (int m = 0; m < 16; ++m) v[m] = row[m * 64 + lane];
  int* op = idx + ((size_t)b0 * NN + p) * KNN;
  for (int r = 0; r < KNN; ++r) {
    double bv = -INFINITY;
    int bj = MM;
#pragma unroll
    for (int m = 0; m < 16; ++m) {
      if (v[m] > bv) { bv = v[m]; bj = m * 64 + lane; }
    }
#pragma unroll
    for (int off = 32; off > 0; off >>= 1) {
      double ov = __shfl_xor(bv, off, 64);
      int oj = __shfl_xor(bj, off, 64);
      if (ov > bv || (ov == bv && oj < bj)) { bv = ov; bj = oj; }
    }
    if (bj < MM && lane == (bj & 63)) v[bj >> 6] = -INFINITY;
    if (lane == 0) op[r] = bj;
  }
}

// ------- per-point feature matmul: out[b,j,o] = sum_c src[b,j,c] * weff[o,c] (f32) -------
// mode 0: weff = w[o,c]; mode 1: weff = w[o,C+c] - w[o,c]
__global__ __launch_bounds__(256) void k_featmm(
    const float* __restrict__ src, int lds_, const float* __restrict__ w, int CW,
    float* __restrict__ out, int C, int O, int mode, int Np) {
  __shared__ float As[16][68];
  __shared__ float Ws[16][68];
  int b = blockIdx.z;
  int j0 = blockIdx.y * 64;
  int o0 = blockIdx.x * 64;
  int tx = threadIdx.x, ty = threadIdx.y;
  int tid = ty * 16 + tx;
  const float* Sb = src + (size_t)b * Np * lds_;
  float acc[4][4] = {};
  for (int c0 = 0; c0 < C; c0 += 16) {
    for (int r = 0; r < 4; ++r) {
      int li = tid + r * 256;
      int row = li >> 4, k = li & 15;
      int c = c0 + k;
      As[k][row] = (c < C) ? Sb[(size_t)(j0 + row) * lds_ + c] : 0.f;
      float wv = 0.f;
      if (c < C) {
        const float* wr = w + (size_t)(o0 + row) * CW;
        wv = mode == 0 ? wr[c] : (wr[C + c] - wr[c]);
      }
      Ws[k][row] = wv;
    }
    __syncthreads();
#pragma unroll
    for (int k = 0; k < 16; ++k) {
      float a_[4], b_[4];
#pragma unroll
      for (int ii = 0; ii < 4; ++ii) a_[ii] = As[k][ty * 4 + ii];
#pragma unroll
      for (int jj = 0; jj < 4; ++jj) b_[jj] = Ws[k][tx * 4 + jj];
#pragma unroll
      for (int ii = 0; ii < 4; ++ii)
#pragma unroll
        for (int jj = 0; jj < 4; ++jj)
          acc[ii][jj] = fmaf(a_[ii], b_[jj], acc[ii][jj]);
    }
    __syncthreads();
  }
  for (int ii = 0; ii < 4; ++ii) {
    int j = j0 + ty * 4 + ii;
    float4 v;
    float* vp = &v.x;
    for (int jj = 0; jj < 4; ++jj) vp[jj] = acc[ii][jj];
    *(float4*)&out[((size_t)b * Np + j) * O + o0 + tx * 4] = v;
  }
}

// ------- fused gather: per (n,o) compute max_k y (y = u[idx]+t), accumulate BN stats -------
__global__ __launch_bounds__(256) void k_gather(
    const float* __restrict__ u, const float* __restrict__ t, const int* __restrict__ idx,
    double* __restrict__ stats, float* __restrict__ mx, int O, int srcNp) {
  __shared__ int lidx[16 * KNN];
  __shared__ double rs[256];
  __shared__ double rq[256];
  int b = blockIdx.y;
  int n0 = blockIdx.x * 16;
  int o0 = blockIdx.z * 64;
  int tid = threadIdx.x;
  int lane = tid & 63, nsl = tid >> 6;
  for (int w = tid; w < 16 * KNN; w += 256)
    lidx[w] = idx[((size_t)b * NN + n0) * KNN + w];
  __syncthreads();
  int oo = o0 + lane;
  double s1 = 0.0, s2 = 0.0;
  for (int ns = nsl; ns < 16; ns += 4) {
    size_t row = (size_t)b * NN + n0 + ns;
    float tv = t[row * O + oo];
    float mxv = -INFINITY, a1 = 0.f, a2 = 0.f;
#pragma unroll
    for (int k = 0; k < KNN; ++k) {
      int j = lidx[ns * KNN + k];
      float yv = u[((size_t)b * srcNp + j) * O + oo] + tv;
      mxv = fmaxf(mxv, yv);
      a1 += yv;
      a2 = fmaf(yv, yv, a2);
    }
    mx[row * O + oo] = mxv;
    s1 += (double)a1;
    s2 += (double)a2;
  }
  rs[tid] = s1;
  rq[tid] = s2;
  __syncthreads();
  if (tid < 64) {
    s1 = rs[tid] + rs[tid + 64] + rs[tid + 128] + rs[tid + 192];
    s2 = rq[tid] + rq[tid + 64] + rq[tid + 128] + rq[tid + 192];
    atomicAdd(&stats[o0 + tid], s1);
    atomicAdd(&stats[O + o0 + tid], s2);
  }
}

// ---------------- fold BN into per-channel scale/shift ----------------
__global__ void k_bnfin(const double* __restrict__ stats, const float* __restrict__ gamma,
                        const float* __restrict__ beta, float* __restrict__ sc,
                        int O, double cnt) {
  int o = threadIdx.x;
  if (o >= O) return;
  double mean = stats[o] / cnt;
  double var = stats[O + o] / cnt - mean * mean;
  if (var < 0.0) var = 0.0;
  double rstd = 1.0 / sqrt(var + 1e-5);
  float s = gamma[o] * (float)rstd;
  float c = beta[o] - (float)mean * s;
  sc[o] = s;
  sc[O + o] = c;
}

// ------- apply BN+lrelu to stored max, write cat slice. s<0 fallback: re-gather min -------
__global__ __launch_bounds__(256) void k_bnapply(
    const float* __restrict__ mx, const float* __restrict__ u, const float* __restrict__ t,
    const int* __restrict__ idx, const float* __restrict__ sc, float* __restrict__ cat,
    int coff, int O, int srcNp) {
  int i = blockIdx.x * 256 + threadIdx.x;
  int total = BB * NN * O;
  if (i >= total) return;
  int oo = i % O;
  int n = (i / O) % NN;
  int b = i / (O * NN);
  float s = sc[oo], c = sc[O + oo];
  float v;
  if (s >= 0.f) {
    v = mx[i];
  } else {  // monotone-decreasing transform needs min_k y (never hit with gamma=1)
    float tv = t[i];
    float mn = INFINITY;
    for (int k = 0; k < KNN; ++k) {
      int j = idx[((size_t)b * NN + n) * KNN + k];
      mn = fminf(mn, u[((size_t)b * srcNp + j) * O + oo] + tv);
    }
    v = mn;
  }
  float a = s * v + c;
  a = (a >= 0.f) ? a : NEG_SLOPE * a;
  cat[((size_t)b * NN + n) * 512 + coff + oo] = a;
}

// ------- layer 5 streaming stats over stored y5 (B,N,512) -------
__global__ __launch_bounds__(256) void k_stats512(
    const float* __restrict__ y5, double* __restrict__ stats) {
  int b = blockIdx.y;
  int n0 = blockIdx.x * 32;
  int tid = threadIdx.x;
  for (int part = 0; part < 2; ++part) {
    int oo = tid + part * 256;
    float a1 = 0.f, a2 = 0.f;
    for (int ns = 0; ns < 32; ++ns) {
      float v = y5[((size_t)b * NN + n0 + ns) * 512 + oo];
      a1 += v;
      a2 = fmaf(v, v, a2);
    }
    atomicAdd(&stats[oo], (double)a1);
    atomicAdd(&stats[512 + oo], (double)a2);
  }
}

// ------- layer 5 streaming finalize: BN+lrelu on stored y5, transpose, f32 store -------
__global__ __launch_bounds__(256) void k_final5b(
    const float* __restrict__ y5, const float* __restrict__ sc, float* __restrict__ out) {
  __shared__ float tile[64][65];
  int b = blockIdx.z;
  int n0 = blockIdx.x * 64;
  int o0 = blockIdx.y * 64;
  int tid = threadIdx.x;
  for (int r = 0; r < 16; ++r) {
    int li = tid + r * 256;
    int nl = li >> 6, ol = li & 63;
    float v = y5[((size_t)b * NN + n0 + nl) * 512 + o0 + ol];
    float a = sc[o0 + ol] * v + sc[512 + o0 + ol];
    a = (a >= 0.f) ? a : NEG_SLOPE * a;
    tile[nl][ol] = a;
  }
  __syncthreads();
  for (int r = 0; r < 16; ++r) {
    int li = tid + r * 256;
    int ol = li >> 6, nl = li & 63;
    out[((size_t)b * 512 + o0 + ol) * NN + n0 + nl] = tile[nl][ol];
  }
}

// ------- fallback layer 5 (CB<2): GEMM+stats recompute pass -------
__global__ __launch_bounds__(256) void k_mmstats(
    const float* __restrict__ src, const float* __restrict__ w,
    double* __restrict__ stats) {
  __shared__ float As[16][68];
  __shared__ float Ws[16][68];
  __shared__ float redS[16][64];
  __shared__ float redQ[16][64];
  int b = blockIdx.z;
  int j0 = blockIdx.y * 64;
  int o0 = blockIdx.x * 64;
  int tx = threadIdx.x, ty = threadIdx.y;
  int tid = ty * 16 + tx;
  const float* Sb = src + (size_t)b * NN * 512;
  float acc[4][4] = {};
  for (int c0 = 0; c0 < 512; c0 += 16) {
    for (int r = 0; r < 4; ++r) {
      int li = tid + r * 256;
      int row = li >> 4, k = li & 15;
      As[k][row] = Sb[(size_t)(j0 + row) * 512 + c0 + k];
      Ws[k][row] = w[(size_t)(o0 + row) * 512 + c0 + k];
    }
    __syncthreads();
#pragma unroll
    for (int k = 0; k < 16; ++k) {
      float a_[4], b_[4];
#pragma unroll
      for (int ii = 0; ii < 4; ++ii) a_[ii] = As[k][ty * 4 + ii];
#pragma unroll
      for (int jj = 0; jj < 4; ++jj) b_[jj] = Ws[k][tx * 4 + jj];
#pragma unroll
      for (int ii = 0; ii < 4; ++ii)
#pragma unroll
        for (int jj = 0; jj < 4; ++jj)
          acc[ii][jj] = fmaf(a_[ii], b_[jj], acc[ii][jj]);
    }
    __syncthreads();
  }
  for (int jj = 0; jj < 4; ++jj) {
    float s = 0.f, q = 0.f;
    for (int ii = 0; ii < 4; ++ii) { float v = acc[ii][jj]; s += v; q += v * v; }
    redS[ty][tx * 4 + jj] = s;
    redQ[ty][tx * 4 + jj] = q;
  }
  __syncthreads();
  if (tid < 64) {
    float s = 0.f, q = 0.f;
    for (int r = 0; r < 16; ++r) { s += redS[r][tid]; q += redQ[r][tid]; }
    atomicAdd(&stats[o0 + tid], (double)s);
    atomicAdd(&stats[512 + o0 + tid], (double)q);
  }
}

// ------- fallback layer 5 (CB<2): recompute GEMM, BN+lrelu, transposed store -------
__global__ __launch_bounds__(256) void k_final5(
    const float* __restrict__ src, const float* __restrict__ w,
    const float* __restrict__ sc, float* __restrict__ out) {
  __shared__ float As[16][68];
  __shared__ float Ws[16][68];
  __shared__ float tile[64][65];
  int b = blockIdx.z;
  int j0 = blockIdx.y * 64;
  int o0 = blockIdx.x * 64;
  int tx = threadIdx.x, ty = threadIdx.y;
  int tid = ty * 16 + tx;
  const float* Sb = src + (size_t)b * NN * 512;
  float acc[4][4] = {};
  for (int c0 = 0; c0 < 512; c0 += 16) {
    for (int r = 0; r < 4; ++r) {
      int li = tid + r * 256;
      int row = li >> 4, k = li & 15;
      As[k][row] = Sb[(size_t)(j0 + row) * 512 + c0 + k];
      Ws[k][row] = w[(size_t)(o0 + row) * 512 + c0 + k];
    }
    __syncthreads();
#pragma unroll
    for (int k = 0; k < 16; ++k) {
      float a_[4], b_[4];
#pragma unroll
      for (int ii = 0; ii < 4; ++ii) a_[ii] = As[k][ty * 4 + ii];
#pragma unroll
      for (int jj = 0; jj < 4; ++jj) b_[jj] = Ws[k][tx * 4 + jj];
#pragma unroll
      for (int ii = 0; ii < 4; ++ii)
#pragma unroll
        for (int jj = 0; jj < 4; ++jj)
          acc[ii][jj] = fmaf(a_[ii], b_[jj], acc[ii][jj]);
    }
    __syncthreads();
  }
  for (int ii = 0; ii < 4; ++ii)
    for (int jj = 0; jj < 4; ++jj) {
      int nl = ty * 4 + ii, ol = tx * 4 + jj;
      float a = sc[o0 + ol] * acc[ii][jj] + sc[512 + o0 + ol];
      a = (a >= 0.f) ? a : NEG_SLOPE * a;
      tile[nl][ol] = a;
    }
  __syncthreads();
  for (int r = 0; r < 16; ++r) {
    int li = tid + r * 256;
    int ol = li >> 6, nl = li & 63;
    out[((size_t)b * 512 + o0 + ol) * NN + j0 + nl] = tile[nl][ol];
  }
}

// =====================================================================================
// f32 in/out. f64 distances (knn tie-exactness vs np ref). Fused gather (max-trick).
// NEW r7: f64 LDS staging in gram (cvt hoisted out of inner loop); symmetric triangular
// gram for layers 1-3 (mirror via LDS transpose); layer 5 stores y5 in U (CB>=2) and
// streams stats+finalize instead of recomputing the GEMM twice.
extern "C" void kernel_launch(void* const* d_in, const int* in_sizes, int n_in,
                              void* d_out, int out_size, void* d_ws, size_t ws_size,
                              hipStream_t stream) {
  const float* x = (const float*)d_in[0];
  const float* y = (const float*)d_in[1];
  const float* w1 = (const float*)d_in[2];
  const float* w2 = (const float*)d_in[3];
  const float* w3 = (const float*)d_in[4];
  const float* w4 = (const float*)d_in[5];
  const float* w5 = (const float*)d_in[6];
  const float* g1 = (const float*)d_in[7];
  const float* b1 = (const float*)d_in[8];
  const float* g2 = (const float*)d_in[9];
  const float* b2 = (const float*)d_in[10];
  const float* g3 = (const float*)d_in[11];
  const float* b3 = (const float*)d_in[12];
  const float* g4 = (const float*)d_in[13];
  const float* b4 = (const float*)d_in[14];
  const float* g5 = (const float*)d_in[15];
  const float* b5 = (const float*)d_in[16];

  char* base = (char*)d_ws;
  size_t off = 0;
  auto alloc = [&](size_t bytes) -> char* {
    char* p = base + off;
    off += (bytes + 255) & ~(size_t)255;
    return p;
  };
  double* st = (double*)alloc(1024 * 8);
  float* sc  = (float*)alloc(1024 * 4);
  double* sq  = (double*)alloc((size_t)BB * NN * 8);
  double* rnx = (double*)alloc((size_t)BB * NN * 8);
  double* rny = (double*)alloc((size_t)BB * MM * 8);
  int*   idxb = (int*)alloc((size_t)BB * NN * KNN * 4);
  float* xs3 = (float*)alloc((size_t)BB * NN * 3 * 4);
  float* ys  = (float*)alloc((size_t)BB * MM * 128 * 4);
  float* cat = (float*)alloc((size_t)BB * NN * 512 * 4);
  size_t ddBatchBytes = (size_t)NN * MM * 8;  // 8 MB per batch (f64)
  size_t avail = (ws_size > off) ? (ws_size - off) : 0;
  int CB = (int)(avail / ddBatchBytes);
  if (CB < 1) CB = 1;
  if (CB > BB) CB = BB;
  char*  U   = alloc((size_t)CB * ddBatchBytes);
  double* DD = (double*)U;                     // dist/simi chunk (f64), dead after topk
  float* tt  = (float*)U;                      // center term (f32, <=8MB), after DD dead
  float* y5  = (float*)U;                      // layer-5 pre-BN (16MB, needs CB>=2)
  float* uu  = (float*)d_out;                  // source term (<=8MB)
  float* mx  = (float*)d_out + (size_t)2 * 1024 * 1024;  // max_k y (<=8MB)
  float* outp = (float*)d_out;

  const dim3 blk2(16, 16);
  const double cntE = (double)BB * NN * KNN;

  // knn: sym=1 -> triangular symmetric euclid gram (A==B); else general MODE
  auto knn = [&](const float* A, int lda, const float* Bm, int ldb,
                 const double* sa, const double* sb, int C, int mode, int sym) {
    for (int b0 = 0; b0 < BB; b0 += CB) {
      int cb = (BB - b0 < CB) ? (BB - b0) : CB;
      if (sym) {
        k_gram_sym<<<dim3(136, 1, cb), blk2, 0, stream>>>(A, lda, sa, DD, C, b0);
      } else {
        dim3 g(MM / 64, NN / 64, cb);
        if (mode == 1) k_gram<1><<<g, blk2, 0, stream>>>(A, lda, Bm, ldb, sa, sb, DD, C, b0);
        else           k_gram<2><<<g, blk2, 0, stream>>>(A, lda, Bm, ldb, sa, sb, DD, C, b0);
      }
      k_topk<<<cb * 256, 256, 0, stream>>>(DD, idxb, b0);
    }
  };

  auto edge_layer = [&](const float* ctr, int ldc, const float* src, int ldsrc, int srcNp,
                        const float* w, int CW, const float* g, const float* bb,
                        int C, int O, int coff) {
    k_featmm<<<dim3(O / 64, 16, 8), blk2, 0, stream>>>(src, ldsrc, w, CW, uu, C, O, 0, srcNp);
    k_featmm<<<dim3(O / 64, 16, 8), blk2, 0, stream>>>(ctr, ldc, w, CW, tt, C, O, 1, NN);
    hipMemsetAsync(st, 0, 1024 * 8, stream);
    k_gather<<<dim3(NN / 16, BB, O / 64), 256, 0, stream>>>(uu, tt, idxb, st, mx, O, srcNp);
    k_bnfin<<<1, O, 0, stream>>>(st, g, bb, sc, O, cntE);
    k_bnapply<<<(BB * NN * O + 255) / 256, 256, 0, stream>>>(mx, uu, tt, idxb, sc, cat,
                                                             coff, O, srcNp);
  };

  // ---- input transposes ----
  k_transpose<<<96, 256, 0, stream>>>(x, xs3, 3, NN);
  k_transpose<<<2048, 256, 0, stream>>>(y, ys, 128, MM);

  // ---- layer 1: C=3, O=64 ----
  k_rowsq<0><<<32, 256, 0, stream>>>(xs3, 3, 3, sq);
  knn(xs3, 3, xs3, 3, sq, sq, 3, 1, 1);
  edge_layer(xs3, 3, xs3, 3, NN, w1, 6, g1, b1, 3, 64, 0);

  // ---- layer 2: x1 = cat[:,0:64], C=64, O=64 ----
  k_rowsq<0><<<32, 256, 0, stream>>>(cat, 512, 64, sq);
  knn(cat, 512, cat, 512, sq, sq, 64, 1, 1);
  edge_layer(cat, 512, cat, 512, NN, w2, 128, g2, b2, 64, 64, 64);

  // ---- layer 3: x2 = cat[:,64:128], C=64, O=128 ----
  k_rowsq<0><<<32, 256, 0, stream>>>(cat + 64, 512, 64, sq);
  knn(cat + 64, 512, cat + 64, 512, sq, sq, 64, 1, 1);
  edge_layer(cat + 64, 512, cat + 64, 512, NN, w3, 128, g3, b3, 64, 128, 128);

  // ---- layer 4 (IA): x3 = cat[:,128:256], src = y (cosine knn), C=128, O=256 ----
  k_rowsq<1><<<32, 256, 0, stream>>>(cat + 128, 512, 128, rnx);
  k_rowsq<1><<<32, 256, 0, stream>>>(ys, 128, 128, rny);
  knn(cat + 128, 512, ys, 128, rnx, rny, 128, 2, 0);
  edge_layer(cat + 128, 512, ys, 128, MM, w4, 256, g4, b4, 128, 256, 256);

  // ---- layer 5: GEMM (C=512,O=512) -> y5, BN over (B,N), lrelu, transposed out ----
  hipMemsetAsync(st, 0, 1024 * 8, stream);
  if (CB >= 2) {
    k_featmm<<<dim3(8, 16, 8), blk2, 0, stream>>>(cat, 512, w5, 512, y5, 512, 512, 0, NN);
    k_stats512<<<dim3(32, 8), 256, 0, stream>>>(y5, st);
    k_bnfin<<<1, 512, 0, stream>>>(st, g5, b5, sc, 512, (double)(BB * NN));
    k_final5b<<<dim3(16, 8, 8), 256, 0, stream>>>(y5, sc, outp);
  } else {
    k_mmstats<<<dim3(8, 16, 8), blk2, 0, stream>>>(cat, w5, st);
    k_bnfin<<<1, 512, 0, stream>>>(st, g5, b5, sc, 512, (double)(BB * NN));
    k_final5<<<dim3(8, 16, 8), blk2, 0, stream>>>(cat, w5, sc, outp);
  }
}

// Round 8
// 819.751 us; speedup vs baseline: 1.4041x; 1.0280x over previous
//
#include <hip/hip_runtime.h>
#include <hip/hip_bf16.h>

#define KNN 20
#define NEG_SLOPE 0.2f

constexpr int BB = 8;
constexpr int NN = 1024;
constexpr int MM = 1024;

// ---------------- transpose f32: (B,C,Np) -> (B,Np,C) ----------------
__global__ __launch_bounds__(256) void k_transpose(
    const float* __restrict__ in, float* __restrict__ out, int C, int Np) {
  int total = BB * C * Np;
  for (int t = blockIdx.x * 256 + threadIdx.x; t < total; t += gridDim.x * 256) {
    int c = t % C;
    int n = (t / C) % Np;
    int b = t / (C * Np);
    out[t] = in[((size_t)b * C + c) * Np + n];
  }
}

// ------- per-point squared norm (RECIP=0) or reciprocal norm (RECIP=1), f64 out -------
template <int RECIP>
__global__ __launch_bounds__(256) void k_rowsq(
    const float* __restrict__ A, int ld, int C, double* __restrict__ sq) {
  int p = blockIdx.x * 256 + threadIdx.x;
  if (p >= BB * NN) return;
  const float* row = A + (size_t)p * ld;
  double s = 0.0;
  for (int c = 0; c < C; ++c) { double v = (double)row[c]; s += v * v; }
  if (RECIP) {
    sq[p] = 1.0 / fmax(sqrt(s), 1e-12);
  } else {
    sq[p] = s;
  }
}

// ---- big-tile f64 gram: 128x128 block, 8x8/thread. batch = blockIdx.x (XCD affinity) ----
// MODE 1: D = 2*dot - sqA_i - sqB_j ; MODE 2: D = dot * rnA_i * rnB_j
template <int MODE>
__global__ __launch_bounds__(256) void k_gram2(
    const float* __restrict__ A, int lda, const float* __restrict__ Bm, int ldb,
    const double* __restrict__ sqA, const double* __restrict__ sqB,
    double* __restrict__ D, int C, int b0) {
  __shared__ double As[16][136];
  __shared__ double Bs[16][136];
  int bg = b0 + blockIdx.x;
  int bl = blockIdx.x;
  int j0 = blockIdx.y * 128;
  int i0 = blockIdx.z * 128;
  const float* Ab = A + (size_t)bg * NN * lda;
  const float* Bb = Bm + (size_t)bg * MM * ldb;
  int tx = threadIdx.x, ty = threadIdx.y;
  int tid = ty * 16 + tx;
  double acc[8][8] = {};
  for (int c0 = 0; c0 < C; c0 += 16) {
    for (int r = 0; r < 2; ++r) {
      int li = tid + r * 256;      // 0..511
      int row = li >> 2;           // 0..127
      int f = (li & 3) * 4;        // c offset 0,4,8,12
      float4 av = *(const float4*)&Ab[(size_t)(i0 + row) * lda + c0 + f];
      As[f + 0][row] = (double)av.x;
      As[f + 1][row] = (double)av.y;
      As[f + 2][row] = (double)av.z;
      As[f + 3][row] = (double)av.w;
      float4 bv = *(const float4*)&Bb[(size_t)(j0 + row) * ldb + c0 + f];
      Bs[f + 0][row] = (double)bv.x;
      Bs[f + 1][row] = (double)bv.y;
      Bs[f + 2][row] = (double)bv.z;
      Bs[f + 3][row] = (double)bv.w;
    }
    __syncthreads();
#pragma unroll
    for (int k = 0; k < 16; ++k) {
      double a_[8], b_[8];
#pragma unroll
      for (int ii = 0; ii < 8; ++ii) a_[ii] = As[k][ty * 8 + ii];
#pragma unroll
      for (int jj = 0; jj < 8; ++jj) b_[jj] = Bs[k][tx * 8 + jj];
#pragma unroll
      for (int ii = 0; ii < 8; ++ii)
#pragma unroll
        for (int jj = 0; jj < 8; ++jj)
          acc[ii][jj] = fma(a_[ii], b_[jj], acc[ii][jj]);
    }
    __syncthreads();
  }
  for (int ii = 0; ii < 8; ++ii) {
    int i = i0 + ty * 8 + ii;
    for (int jj = 0; jj < 8; ++jj) {
      int j = j0 + tx * 8 + jj;
      double r = acc[ii][jj];
      if (MODE == 1) r = 2.0 * r - sqA[bg * NN + i] - sqB[bg * NN + j];
      if (MODE == 2) r = r * sqA[bg * NN + i] * sqB[bg * NN + j];
      D[((size_t)bl * NN + i) * MM + j] = r;
    }
  }
}

// ------- symmetric euclidean gram (A==B): triangular blocks; batch = blockIdx.x -------
__global__ __launch_bounds__(256) void k_gram_sym(
    const float* __restrict__ A, int lda, const double* __restrict__ sqA,
    double* __restrict__ D, int C, int b0) {
  __shared__ double As[16][68];
  __shared__ double Bs[16][68];
  __shared__ double T[64][65];
  int p = blockIdx.y;  // 0..135 triangular pair index
  int r = (int)((sqrtf(8.f * p + 1.f) - 1.f) * 0.5f);
  while ((r + 1) * (r + 2) / 2 <= p) ++r;
  while (r * (r + 1) / 2 > p) --r;
  int cc = p - r * (r + 1) / 2;
  int i0 = r * 64, j0 = cc * 64;
  int bg = b0 + blockIdx.x;
  int bl = blockIdx.x;
  const float* Ab = A + (size_t)bg * NN * lda;
  int tx = threadIdx.x, ty = threadIdx.y;
  int tid = ty * 16 + tx;
  double acc[4][4] = {};
  for (int c0 = 0; c0 < C; c0 += 16) {
    for (int rr = 0; rr < 4; ++rr) {
      int li = tid + rr * 256;
      int row = li >> 4, k = li & 15;
      int c = c0 + k;
      As[k][row] = (c < C) ? (double)Ab[(size_t)(i0 + row) * lda + c] : 0.0;
      Bs[k][row] = (c < C) ? (double)Ab[(size_t)(j0 + row) * lda + c] : 0.0;
    }
    __syncthreads();
#pragma unroll
    for (int k = 0; k < 16; ++k) {
      double a_[4], b_[4];
#pragma unroll
      for (int ii = 0; ii < 4; ++ii) a_[ii] = As[k][ty * 4 + ii];
#pragma unroll
      for (int jj = 0; jj < 4; ++jj) b_[jj] = Bs[k][tx * 4 + jj];
#pragma unroll
      for (int ii = 0; ii < 4; ++ii)
#pragma unroll
        for (int jj = 0; jj < 4; ++jj)
          acc[ii][jj] = fma(a_[ii], b_[jj], acc[ii][jj]);
    }
    __syncthreads();
  }
  for (int ii = 0; ii < 4; ++ii) {
    int i = i0 + ty * 4 + ii;
    for (int jj = 0; jj < 4; ++jj) {
      int j = j0 + tx * 4 + jj;
      double v = 2.0 * acc[ii][jj] - sqA[bg * NN + i] - sqA[bg * NN + j];
      D[((size_t)bl * NN + i) * MM + j] = v;
      T[tx * 4 + jj][ty * 4 + ii] = v;
    }
  }
  if (i0 != j0) {
    __syncthreads();
    for (int rr = 0; rr < 16; ++rr) {
      int li = tid + rr * 256;
      int jrow = li >> 6, il = li & 63;
      D[((size_t)bl * NN + j0 + jrow) * MM + i0 + il] = T[jrow][il];
    }
  }
}

// ------- top-20 per row over the chunk, f64 (largest value, tie -> lowest index) -------
__global__ __launch_bounds__(256) void k_topk(const double* __restrict__ D,
                                              int* __restrict__ idx, int b0) {
  int wave = threadIdx.x >> 6;
  int lane = threadIdx.x & 63;
  int p = blockIdx.x * 4 + wave;
  const double* row = D + (size_t)p * MM;
  double v[16];
#pragma unroll
  for (int m = 0; m < 16; ++m) v[m] = row[m * 64 + lane];
  int* op = idx + ((size_t)b0 * NN + p) * KNN;
  for (int r = 0; r < KNN; ++r) {
    double bv = -INFINITY;
    int bj = MM;
#pragma unroll
    for (int m = 0; m < 16; ++m) {
      if (v[m] > bv) { bv = v[m]; bj = m * 64 + lane; }
    }
#pragma unroll
    for (int off = 32; off > 0; off >>= 1) {
      double ov = __shfl_xor(bv, off, 64);
      int oj = __shfl_xor(bj, off, 64);
      if (ov > bv || (ov == bv && oj < bj)) { bv = ov; bj = oj; }
    }
    if (bj < MM && lane == (bj & 63)) v[bj >> 6] = -INFINITY;
    if (lane == 0) op[r] = bj;
  }
}

// ------- per-point feature matmul (64x64 tile): batch = blockIdx.x (XCD affinity) -------
// mode 0: weff = w[o,c]; mode 1: weff = w[o,C+c] - w[o,c]
__global__ __launch_bounds__(256) void k_featmm(
    const float* __restrict__ src, int lds_, const float* __restrict__ w, int CW,
    float* __restrict__ out, int C, int O, int mode, int Np) {
  __shared__ float As[16][68];
  __shared__ float Ws[16][68];
  int b = blockIdx.x;
  int o0 = blockIdx.y * 64;
  int j0 = blockIdx.z * 64;
  int tx = threadIdx.x, ty = threadIdx.y;
  int tid = ty * 16 + tx;
  const float* Sb = src + (size_t)b * Np * lds_;
  float acc[4][4] = {};
  for (int c0 = 0; c0 < C; c0 += 16) {
    for (int r = 0; r < 4; ++r) {
      int li = tid + r * 256;
      int row = li >> 4, k = li & 15;
      int c = c0 + k;
      As[k][row] = (c < C) ? Sb[(size_t)(j0 + row) * lds_ + c] : 0.f;
      float wv = 0.f;
      if (c < C) {
        const float* wr = w + (size_t)(o0 + row) * CW;
        wv = mode == 0 ? wr[c] : (wr[C + c] - wr[c]);
      }
      Ws[k][row] = wv;
    }
    __syncthreads();
#pragma unroll
    for (int k = 0; k < 16; ++k) {
      float a_[4], b_[4];
#pragma unroll
      for (int ii = 0; ii < 4; ++ii) a_[ii] = As[k][ty * 4 + ii];
#pragma unroll
      for (int jj = 0; jj < 4; ++jj) b_[jj] = Ws[k][tx * 4 + jj];
#pragma unroll
      for (int ii = 0; ii < 4; ++ii)
#pragma unroll
        for (int jj = 0; jj < 4; ++jj)
          acc[ii][jj] = fmaf(a_[ii], b_[jj], acc[ii][jj]);
    }
    __syncthreads();
  }
  for (int ii = 0; ii < 4; ++ii) {
    int j = j0 + ty * 4 + ii;
    float4 v;
    float* vp = &v.x;
    for (int jj = 0; jj < 4; ++jj) vp[jj] = acc[ii][jj];
    *(float4*)&out[((size_t)b * Np + j) * O + o0 + tx * 4] = v;
  }
}

// ---- layer-5 GEMM: C=512,O=512, 128x128 tile, 8x8/thread, batch = blockIdx.x ----
__global__ __launch_bounds__(256) void k_gemm5(
    const float* __restrict__ src, const float* __restrict__ w, float* __restrict__ out) {
  __shared__ float As[16][132];
  __shared__ float Ws[16][132];
  int b = blockIdx.x;
  int j0 = blockIdx.y * 128;
  int o0 = blockIdx.z * 128;
  int tx = threadIdx.x, ty = threadIdx.y;
  int tid = ty * 16 + tx;
  const float* Sb = src + (size_t)b * NN * 512;
  float acc[8][8] = {};
  for (int c0 = 0; c0 < 512; c0 += 16) {
    for (int r = 0; r < 2; ++r) {
      int li = tid + r * 256;
      int row = li >> 2;
      int f = (li & 3) * 4;
      float4 av = *(const float4*)&Sb[(size_t)(j0 + row) * 512 + c0 + f];
      As[f + 0][row] = av.x;
      As[f + 1][row] = av.y;
      As[f + 2][row] = av.z;
      As[f + 3][row] = av.w;
      float4 wv = *(const float4*)&w[(size_t)(o0 + row) * 512 + c0 + f];
      Ws[f + 0][row] = wv.x;
      Ws[f + 1][row] = wv.y;
      Ws[f + 2][row] = wv.z;
      Ws[f + 3][row] = wv.w;
    }
    __syncthreads();
#pragma unroll
    for (int k = 0; k < 16; ++k) {
      float a_[8], b_[8];
#pragma unroll
      for (int ii = 0; ii < 8; ++ii) a_[ii] = As[k][ty * 8 + ii];
#pragma unroll
      for (int jj = 0; jj < 8; ++jj) b_[jj] = Ws[k][tx * 8 + jj];
#pragma unroll
      for (int ii = 0; ii < 8; ++ii)
#pragma unroll
        for (int jj = 0; jj < 8; ++jj)
          acc[ii][jj] = fmaf(a_[ii], b_[jj], acc[ii][jj]);
    }
    __syncthreads();
  }
  for (int ii = 0; ii < 8; ++ii) {
    int j = j0 + ty * 8 + ii;
    float* orow = &out[((size_t)b * NN + j) * 512 + o0 + tx * 8];
    float4 v0, v1;
    v0.x = acc[ii][0]; v0.y = acc[ii][1]; v0.z = acc[ii][2]; v0.w = acc[ii][3];
    v1.x = acc[ii][4]; v1.y = acc[ii][5]; v1.z = acc[ii][6]; v1.w = acc[ii][7];
    *(float4*)orow = v0;
    *(float4*)(orow + 4) = v1;
  }
}

// ------- fused gather: per (n,o) compute max_k y, accumulate BN stats; b = blockIdx.x -------
__global__ __launch_bounds__(256) void k_gather(
    const float* __restrict__ u, const float* __restrict__ t, const int* __restrict__ idx,
    double* __restrict__ stats, float* __restrict__ mx, int O, int srcNp) {
  __shared__ int lidx[16 * KNN];
  __shared__ double rs[256];
  __shared__ double rq[256];
  int b = blockIdx.x;
  int n0 = blockIdx.y * 16;
  int o0 = blockIdx.z * 64;
  int tid = threadIdx.x;
  int lane = tid & 63, nsl = tid >> 6;
  for (int w = tid; w < 16 * KNN; w += 256)
    lidx[w] = idx[((size_t)b * NN + n0) * KNN + w];
  __syncthreads();
  int oo = o0 + lane;
  double s1 = 0.0, s2 = 0.0;
  for (int ns = nsl; ns < 16; ns += 4) {
    size_t row = (size_t)b * NN + n0 + ns;
    float tv = t[row * O + oo];
    float mxv = -INFINITY, a1 = 0.f, a2 = 0.f;
#pragma unroll
    for (int k = 0; k < KNN; ++k) {
      int j = lidx[ns * KNN + k];
      float yv = u[((size_t)b * srcNp + j) * O + oo] + tv;
      mxv = fmaxf(mxv, yv);
      a1 += yv;
      a2 = fmaf(yv, yv, a2);
    }
    mx[row * O + oo] = mxv;
    s1 += (double)a1;
    s2 += (double)a2;
  }
  rs[tid] = s1;
  rq[tid] = s2;
  __syncthreads();
  if (tid < 64) {
    s1 = rs[tid] + rs[tid + 64] + rs[tid + 128] + rs[tid + 192];
    s2 = rq[tid] + rq[tid + 64] + rq[tid + 128] + rq[tid + 192];
    atomicAdd(&stats[o0 + tid], s1);
    atomicAdd(&stats[O + o0 + tid], s2);
  }
}

// ---------------- fold BN into per-channel scale/shift ----------------
__global__ void k_bnfin(const double* __restrict__ stats, const float* __restrict__ gamma,
                        const float* __restrict__ beta, float* __restrict__ sc,
                        int O, double cnt) {
  int o = threadIdx.x;
  if (o >= O) return;
  double mean = stats[o] / cnt;
  double var = stats[O + o] / cnt - mean * mean;
  if (var < 0.0) var = 0.0;
  double rstd = 1.0 / sqrt(var + 1e-5);
  float s = gamma[o] * (float)rstd;
  float c = beta[o] - (float)mean * s;
  sc[o] = s;
  sc[O + o] = c;
}

// ------- apply BN+lrelu to stored max, write cat slice. s<0 fallback: re-gather min -------
__global__ __launch_bounds__(256) void k_bnapply(
    const float* __restrict__ mx, const float* __restrict__ u, const float* __restrict__ t,
    const int* __restrict__ idx, const float* __restrict__ sc, float* __restrict__ cat,
    int coff, int O, int srcNp) {
  int i = blockIdx.x * 256 + threadIdx.x;
  int total = BB * NN * O;
  if (i >= total) return;
  int oo = i % O;
  int n = (i / O) % NN;
  int b = i / (O * NN);
  float s = sc[oo], c = sc[O + oo];
  float v;
  if (s >= 0.f) {
    v = mx[i];
  } else {  // monotone-decreasing transform needs min_k y (never hit with gamma=1)
    float tv = t[i];
    float mn = INFINITY;
    for (int k = 0; k < KNN; ++k) {
      int j = idx[((size_t)b * NN + n) * KNN + k];
      mn = fminf(mn, u[((size_t)b * srcNp + j) * O + oo] + tv);
    }
    v = mn;
  }
  float a = s * v + c;
  a = (a >= 0.f) ? a : NEG_SLOPE * a;
  cat[((size_t)b * NN + n) * 512 + coff + oo] = a;
}

// ------- layer 5 streaming stats over stored y5 (B,N,512) -------
__global__ __launch_bounds__(256) void k_stats512(
    const float* __restrict__ y5, double* __restrict__ stats) {
  int b = blockIdx.y;
  int n0 = blockIdx.x * 32;
  int tid = threadIdx.x;
  for (int part = 0; part < 2; ++part) {
    int oo = tid + part * 256;
    float a1 = 0.f, a2 = 0.f;
    for (int ns = 0; ns < 32; ++ns) {
      float v = y5[((size_t)b * NN + n0 + ns) * 512 + oo];
      a1 += v;
      a2 = fmaf(v, v, a2);
    }
    atomicAdd(&stats[oo], (double)a1);
    atomicAdd(&stats[512 + oo], (double)a2);
  }
}

// ------- layer 5 streaming finalize: BN+lrelu on stored y5, transpose, f32 store -------
__global__ __launch_bounds__(256) void k_final5b(
    const float* __restrict__ y5, const float* __restrict__ sc, float* __restrict__ out) {
  __shared__ float tile[64][65];
  int b = blockIdx.z;
  int n0 = blockIdx.x * 64;
  int o0 = blockIdx.y * 64;
  int tid = threadIdx.x;
  for (int r = 0; r < 16; ++r) {
    int li = tid + r * 256;
    int nl = li >> 6, ol = li & 63;
    float v = y5[((size_t)b * NN + n0 + nl) * 512 + o0 + ol];
    float a = sc[o0 + ol] * v + sc[512 + o0 + ol];
    a = (a >= 0.f) ? a : NEG_SLOPE * a;
    tile[nl][ol] = a;
  }
  __syncthreads();
  for (int r = 0; r < 16; ++r) {
    int li = tid + r * 256;
    int ol = li >> 6, nl = li & 63;
    out[((size_t)b * 512 + o0 + ol) * NN + n0 + nl] = tile[nl][ol];
  }
}

// ------- fallback layer 5 (CB<2): GEMM+stats recompute pass -------
__global__ __launch_bounds__(256) void k_mmstats(
    const float* __restrict__ src, const float* __restrict__ w,
    double* __restrict__ stats) {
  __shared__ float As[16][68];
  __shared__ float Ws[16][68];
  __shared__ float redS[16][64];
  __shared__ float redQ[16][64];
  int b = blockIdx.z;
  int j0 = blockIdx.y * 64;
  int o0 = blockIdx.x * 64;
  int tx = threadIdx.x, ty = threadIdx.y;
  int tid = ty * 16 + tx;
  const float* Sb = src + (size_t)b * NN * 512;
  float acc[4][4] = {};
  for (int c0 = 0; c0 < 512; c0 += 16) {
    for (int r = 0; r < 4; ++r) {
      int li = tid + r * 256;
      int row = li >> 4, k = li & 15;
      As[k][row] = Sb[(size_t)(j0 + row) * 512 + c0 + k];
      Ws[k][row] = w[(size_t)(o0 + row) * 512 + c0 + k];
    }
    __syncthreads();
#pragma unroll
    for (int k = 0; k < 16; ++k) {
      float a_[4], b_[4];
#pragma unroll
      for (int ii = 0; ii < 4; ++ii) a_[ii] = As[k][ty * 4 + ii];
#pragma unroll
      for (int jj = 0; jj < 4; ++jj) b_[jj] = Ws[k][tx * 4 + jj];
#pragma unroll
      for (int ii = 0; ii < 4; ++ii)
#pragma unroll
        for (int jj = 0; jj < 4; ++jj)
          acc[ii][jj] = fmaf(a_[ii], b_[jj], acc[ii][jj]);
    }
    __syncthreads();
  }
  for (int jj = 0; jj < 4; ++jj) {
    float s = 0.f, q = 0.f;
    for (int ii = 0; ii < 4; ++ii) { float v = acc[ii][jj]; s += v; q += v * v; }
    redS[ty][tx * 4 + jj] = s;
    redQ[ty][tx * 4 + jj] = q;
  }
  __syncthreads();
  if (tid < 64) {
    float s = 0.f, q = 0.f;
    for (int r = 0; r < 16; ++r) { s += redS[r][tid]; q += redQ[r][tid]; }
    atomicAdd(&stats[o0 + tid], (double)s);
    atomicAdd(&stats[512 + o0 + tid], (double)q);
  }
}

// ------- fallback layer 5 (CB<2): recompute GEMM, BN+lrelu, transposed store -------
__global__ __launch_bounds__(256) void k_final5(
    const float* __restrict__ src, const float* __restrict__ w,
    const float* __restrict__ sc, float* __restrict__ out) {
  __shared__ float As[16][68];
  __shared__ float Ws[16][68];
  __shared__ float tile[64][65];
  int b = blockIdx.z;
  int j0 = blockIdx.y * 64;
  int o0 = blockIdx.x * 64;
  int tx = threadIdx.x, ty = threadIdx.y;
  int tid = ty * 16 + tx;
  const float* Sb = src + (size_t)b * NN * 512;
  float acc[4][4] = {};
  for (int c0 = 0; c0 < 512; c0 += 16) {
    for (int r = 0; r < 4; ++r) {
      int li = tid + r * 256;
      int row = li >> 4, k = li & 15;
      As[k][row] = Sb[(size_t)(j0 + row) * 512 + c0 + k];
      Ws[k][row] = w[(size_t)(o0 + row) * 512 + c0 + k];
    }
    __syncthreads();
#pragma unroll
    for (int k = 0; k < 16; ++k) {
      float a_[4], b_[4];
#pragma unroll
      for (int ii = 0; ii < 4; ++ii) a_[ii] = As[k][ty * 4 + ii];
#pragma unroll
      for (int jj = 0; jj < 4; ++jj) b_[jj] = Ws[k][tx * 4 + jj];
#pragma unroll
      for (int ii = 0; ii < 4; ++ii)
#pragma unroll
        for (int jj = 0; jj < 4; ++jj)
          acc[ii][jj] = fmaf(a_[ii], b_[jj], acc[ii][jj]);
    }
    __syncthreads();
  }
  for (int ii = 0; ii < 4; ++ii)
    for (int jj = 0; jj < 4; ++jj) {
      int nl = ty * 4 + ii, ol = tx * 4 + jj;
      float a = sc[o0 + ol] * acc[ii][jj] + sc[512 + o0 + ol];
      a = (a >= 0.f) ? a : NEG_SLOPE * a;
      tile[nl][ol] = a;
    }
  __syncthreads();
  for (int r = 0; r < 16; ++r) {
    int li = tid + r * 256;
    int ol = li >> 6, nl = li & 63;
    out[((size_t)b * 512 + o0 + ol) * NN + j0 + nl] = tile[nl][ol];
  }
}

// =====================================================================================
// f32 in/out. f64 distances. Fused gather (max-trick). r8: 128x128-tile L5 GEMM
// (k_gemm5) + 128x128 f64 L4 gram (k_gram2), batch-fastest block order everywhere for
// XCD L2 affinity (8 batches == 8 XCDs).
extern "C" void kernel_launch(void* const* d_in, const int* in_sizes, int n_in,
                              void* d_out, int out_size, void* d_ws, size_t ws_size,
                              hipStream_t stream) {
  const float* x = (const float*)d_in[0];
  const float* y = (const float*)d_in[1];
  const float* w1 = (const float*)d_in[2];
  const float* w2 = (const float*)d_in[3];
  const float* w3 = (const float*)d_in[4];
  const float* w4 = (const float*)d_in[5];
  const float* w5 = (const float*)d_in[6];
  const float* g1 = (const float*)d_in[7];
  const float* b1 = (const float*)d_in[8];
  const float* g2 = (const float*)d_in[9];
  const float* b2 = (const float*)d_in[10];
  const float* g3 = (const float*)d_in[11];
  const float* b3 = (const float*)d_in[12];
  const float* g4 = (const float*)d_in[13];
  const float* b4 = (const float*)d_in[14];
  const float* g5 = (const float*)d_in[15];
  const float* b5 = (const float*)d_in[16];

  char* base = (char*)d_ws;
  size_t off = 0;
  auto alloc = [&](size_t bytes) -> char* {
    char* p = base + off;
    off += (bytes + 255) & ~(size_t)255;
    return p;
  };
  double* st = (double*)alloc(1024 * 8);
  float* sc  = (float*)alloc(1024 * 4);
  double* sq  = (double*)alloc((size_t)BB * NN * 8);
  double* rnx = (double*)alloc((size_t)BB * NN * 8);
  double* rny = (double*)alloc((size_t)BB * MM * 8);
  int*   idxb = (int*)alloc((size_t)BB * NN * KNN * 4);
  float* xs3 = (float*)alloc((size_t)BB * NN * 3 * 4);
  float* ys  = (float*)alloc((size_t)BB * MM * 128 * 4);
  float* cat = (float*)alloc((size_t)BB * NN * 512 * 4);
  size_t ddBatchBytes = (size_t)NN * MM * 8;  // 8 MB per batch (f64)
  size_t avail = (ws_size > off) ? (ws_size - off) : 0;
  int CB = (int)(avail / ddBatchBytes);
  if (CB < 1) CB = 1;
  if (CB > BB) CB = BB;
  char*  U   = alloc((size_t)CB * ddBatchBytes);
  double* DD = (double*)U;                     // dist/simi chunk (f64), dead after topk
  float* tt  = (float*)U;                      // center term (f32, <=8MB), after DD dead
  float* y5  = (float*)U;                      // layer-5 pre-BN (16MB, needs CB>=2)
  float* uu  = (float*)d_out;                  // source term (<=8MB)
  float* mx  = (float*)d_out + (size_t)2 * 1024 * 1024;  // max_k y (<=8MB)
  float* outp = (float*)d_out;

  const dim3 blk2(16, 16);
  const double cntE = (double)BB * NN * KNN;

  // knn: sym=1 -> triangular symmetric euclid gram (A==B); else general 128-tile MODE
  auto knn = [&](const float* A, int lda, const float* Bm, int ldb,
                 const double* sa, const double* sb, int C, int mode, int sym) {
    for (int b0 = 0; b0 < BB; b0 += CB) {
      int cb = (BB - b0 < CB) ? (BB - b0) : CB;
      if (sym) {
        k_gram_sym<<<dim3(cb, 136), blk2, 0, stream>>>(A, lda, sa, DD, C, b0);
      } else {
        dim3 g(cb, MM / 128, NN / 128);
        if (mode == 1) k_gram2<1><<<g, blk2, 0, stream>>>(A, lda, Bm, ldb, sa, sb, DD, C, b0);
        else           k_gram2<2><<<g, blk2, 0, stream>>>(A, lda, Bm, ldb, sa, sb, DD, C, b0);
      }
      k_topk<<<cb * 256, 256, 0, stream>>>(DD, idxb, b0);
    }
  };

  auto edge_layer = [&](const float* ctr, int ldc, const float* src, int ldsrc, int srcNp,
                        const float* w, int CW, const float* g, const float* bb,
                        int C, int O, int coff) {
    k_featmm<<<dim3(8, O / 64, 16), blk2, 0, stream>>>(src, ldsrc, w, CW, uu, C, O, 0, srcNp);
    k_featmm<<<dim3(8, O / 64, 16), blk2, 0, stream>>>(ctr, ldc, w, CW, tt, C, O, 1, NN);
    hipMemsetAsync(st, 0, 1024 * 8, stream);
    k_gather<<<dim3(BB, NN / 16, O / 64), 256, 0, stream>>>(uu, tt, idxb, st, mx, O, srcNp);
    k_bnfin<<<1, O, 0, stream>>>(st, g, bb, sc, O, cntE);
    k_bnapply<<<(BB * NN * O + 255) / 256, 256, 0, stream>>>(mx, uu, tt, idxb, sc, cat,
                                                             coff, O, srcNp);
  };

  // ---- input transposes ----
  k_transpose<<<96, 256, 0, stream>>>(x, xs3, 3, NN);
  k_transpose<<<2048, 256, 0, stream>>>(y, ys, 128, MM);

  // ---- layer 1: C=3, O=64 ----
  k_rowsq<0><<<32, 256, 0, stream>>>(xs3, 3, 3, sq);
  knn(xs3, 3, xs3, 3, sq, sq, 3, 1, 1);
  edge_layer(xs3, 3, xs3, 3, NN, w1, 6, g1, b1, 3, 64, 0);

  // ---- layer 2: x1 = cat[:,0:64], C=64, O=64 ----
  k_rowsq<0><<<32, 256, 0, stream>>>(cat, 512, 64, sq);
  knn(cat, 512, cat, 512, sq, sq, 64, 1, 1);
  edge_layer(cat, 512, cat, 512, NN, w2, 128, g2, b2, 64, 64, 64);

  // ---- layer 3: x2 = cat[:,64:128], C=64, O=128 ----
  k_rowsq<0><<<32, 256, 0, stream>>>(cat + 64, 512, 64, sq);
  knn(cat + 64, 512, cat + 64, 512, sq, sq, 64, 1, 1);
  edge_layer(cat + 64, 512, cat + 64, 512, NN, w3, 128, g3, b3, 64, 128, 128);

  // ---- layer 4 (IA): x3 = cat[:,128:256], src = y (cosine knn), C=128, O=256 ----
  k_rowsq<1><<<32, 256, 0, stream>>>(cat + 128, 512, 128, rnx);
  k_rowsq<1><<<32, 256, 0, stream>>>(ys, 128, 128, rny);
  knn(cat + 128, 512, ys, 128, rnx, rny, 128, 2, 0);
  edge_layer(cat + 128, 512, ys, 128, MM, w4, 256, g4, b4, 128, 256, 256);

  // ---- layer 5: GEMM (C=512,O=512) -> y5, BN over (B,N), lrelu, transposed out ----
  hipMemsetAsync(st, 0, 1024 * 8, stream);
  if (CB >= 2) {
    k_gemm5<<<dim3(8, 8, 4), blk2, 0, stream>>>(cat, w5, y5);
    k_stats512<<<dim3(32, 8), 256, 0, stream>>>(y5, st);
    k_bnfin<<<1, 512, 0, stream>>>(st, g5, b5, sc, 512, (double)(BB * NN));
    k_final5b<<<dim3(16, 8, 8), 256, 0, stream>>>(y5, sc, outp);
  } else {
    k_mmstats<<<dim3(8, 16, 8), blk2, 0, stream>>>(cat, w5, st);
    k_bnfin<<<1, 512, 0, stream>>>(st, g5, b5, sc, 512, (double)(BB * NN));
    k_final5<<<dim3(8, 16, 8), blk2, 0, stream>>>(cat, w5, sc, outp);
  }
}

// Round 9
// 781.742 us; speedup vs baseline: 1.4723x; 1.0486x over previous
//
#include <hip/hip_runtime.h>
#include <hip/hip_bf16.h>

#define KNN 20
#define NEG_SLOPE 0.2f

constexpr int BB = 8;
constexpr int NN = 1024;
constexpr int MM = 1024;

// ---------------- transpose f32: (B,C,Np) -> (B,Np,C) ----------------
__global__ __launch_bounds__(256) void k_transpose(
    const float* __restrict__ in, float* __restrict__ out, int C, int Np) {
  int total = BB * C * Np;
  for (int t = blockIdx.x * 256 + threadIdx.x; t < total; t += gridDim.x * 256) {
    int c = t % C;
    int n = (t / C) % Np;
    int b = t / (C * Np);
    out[t] = in[((size_t)b * C + c) * Np + n];
  }
}

// ------- per-point squared norm (RECIP=0) or reciprocal norm (RECIP=1), f64 out -------
template <int RECIP>
__global__ __launch_bounds__(256) void k_rowsq(
    const float* __restrict__ A, int ld, int C, double* __restrict__ sq) {
  int p = blockIdx.x * 256 + threadIdx.x;
  if (p >= BB * NN) return;
  const float* row = A + (size_t)p * ld;
  double s = 0.0;
  for (int c = 0; c < C; ++c) { double v = (double)row[c]; s += v * v; }
  if (RECIP) {
    sq[p] = 1.0 / fmax(sqrt(s), 1e-12);
  } else {
    sq[p] = s;
  }
}

// ---- fused L1 knn (C=3): all points in LDS, f64 distances in-register, topk direct ----
// FMA sequence identical to the gram kernels (k=0,1,2 ascending, zero-init acc).
__global__ __launch_bounds__(256) void k_knn3(
    const float* __restrict__ xs3, const double* __restrict__ sq, int* __restrict__ idx) {
  __shared__ float P[NN * 3];
  int b = blockIdx.x;
  const float* Xb = xs3 + (size_t)b * NN * 3;
  int tid = threadIdx.x;
  for (int t = tid; t < NN * 3; t += 256) P[t] = Xb[t];
  __syncthreads();
  int wave = tid >> 6, lane = tid & 63;
  int i = blockIdx.y * 4 + wave;
  double xi = (double)P[i * 3], yi = (double)P[i * 3 + 1], zi = (double)P[i * 3 + 2];
  double sqi = sq[b * NN + i];
  double v[16];
#pragma unroll
  for (int m = 0; m < 16; ++m) {
    int j = m * 64 + lane;
    double d = fma(xi, (double)P[j * 3], 0.0);
    d = fma(yi, (double)P[j * 3 + 1], d);
    d = fma(zi, (double)P[j * 3 + 2], d);
    v[m] = 2.0 * d - sqi - sq[b * NN + j];
  }
  int* op = idx + ((size_t)b * NN + i) * KNN;
  for (int r = 0; r < KNN; ++r) {
    double bv = -INFINITY;
    int bj = MM;
#pragma unroll
    for (int m = 0; m < 16; ++m) {
      if (v[m] > bv) { bv = v[m]; bj = m * 64 + lane; }
    }
#pragma unroll
    for (int off = 32; off > 0; off >>= 1) {
      double ov = __shfl_xor(bv, off, 64);
      int oj = __shfl_xor(bj, off, 64);
      if (ov > bv || (ov == bv && oj < bj)) { bv = ov; bj = oj; }
    }
    if (bj < MM && lane == (bj & 63)) v[bj >> 6] = -INFINITY;
    if (lane == 0) op[r] = bj;
  }
}

// ---- big-tile f64 gram: 128x128 block, 8x8/thread, strided-j (conflict-free LDS) ----
// MODE 1: D = 2*dot - sqA_i - sqB_j ; MODE 2: D = dot * rnA_i * rnB_j
template <int MODE>
__global__ __launch_bounds__(256) void k_gram2(
    const float* __restrict__ A, int lda, const float* __restrict__ Bm, int ldb,
    const double* __restrict__ sqA, const double* __restrict__ sqB,
    double* __restrict__ D, int C, int b0) {
  __shared__ double As[16][136];
  __shared__ double Bs[16][136];
  int bg = b0 + blockIdx.x;
  int bl = blockIdx.x;
  int j0 = blockIdx.y * 128;
  int i0 = blockIdx.z * 128;
  const float* Ab = A + (size_t)bg * NN * lda;
  const float* Bb = Bm + (size_t)bg * MM * ldb;
  int tx = threadIdx.x, ty = threadIdx.y;
  int tid = ty * 16 + tx;
  double acc[8][8] = {};
  for (int c0 = 0; c0 < C; c0 += 16) {
    for (int r = 0; r < 2; ++r) {
      int li = tid + r * 256;
      int row = li >> 2;
      int f = (li & 3) * 4;
      float4 av = *(const float4*)&Ab[(size_t)(i0 + row) * lda + c0 + f];
      As[f + 0][row] = (double)av.x;
      As[f + 1][row] = (double)av.y;
      As[f + 2][row] = (double)av.z;
      As[f + 3][row] = (double)av.w;
      float4 bv = *(const float4*)&Bb[(size_t)(j0 + row) * ldb + c0 + f];
      Bs[f + 0][row] = (double)bv.x;
      Bs[f + 1][row] = (double)bv.y;
      Bs[f + 2][row] = (double)bv.z;
      Bs[f + 3][row] = (double)bv.w;
    }
    __syncthreads();
#pragma unroll
    for (int k = 0; k < 16; ++k) {
      double a_[8], b_[8];
#pragma unroll
      for (int ii = 0; ii < 8; ++ii) a_[ii] = As[k][ty * 8 + ii];
#pragma unroll
      for (int jj = 0; jj < 8; ++jj) b_[jj] = Bs[k][jj * 16 + tx];
#pragma unroll
      for (int ii = 0; ii < 8; ++ii)
#pragma unroll
        for (int jj = 0; jj < 8; ++jj)
          acc[ii][jj] = fma(a_[ii], b_[jj], acc[ii][jj]);
    }
    __syncthreads();
  }
  for (int ii = 0; ii < 8; ++ii) {
    int i = i0 + ty * 8 + ii;
    for (int jj = 0; jj < 8; ++jj) {
      int j = j0 + jj * 16 + tx;
      double r = acc[ii][jj];
      if (MODE == 1) r = 2.0 * r - sqA[bg * NN + i] - sqB[bg * NN + j];
      if (MODE == 2) r = r * sqA[bg * NN + i] * sqB[bg * NN + j];
      D[((size_t)bl * NN + i) * MM + j] = r;
    }
  }
}

// ------- symmetric euclidean gram (A==B): triangular blocks, strided-j mapping -------
__global__ __launch_bounds__(256) void k_gram_sym(
    const float* __restrict__ A, int lda, const double* __restrict__ sqA,
    double* __restrict__ D, int C, int b0) {
  __shared__ double As[16][68];
  __shared__ double Bs[16][68];
  __shared__ double T[64][65];
  int p = blockIdx.y;  // 0..135 triangular pair index
  int r = (int)((sqrtf(8.f * p + 1.f) - 1.f) * 0.5f);
  while ((r + 1) * (r + 2) / 2 <= p) ++r;
  while (r * (r + 1) / 2 > p) --r;
  int cc = p - r * (r + 1) / 2;
  int i0 = r * 64, j0 = cc * 64;
  int bg = b0 + blockIdx.x;
  int bl = blockIdx.x;
  const float* Ab = A + (size_t)bg * NN * lda;
  int tx = threadIdx.x, ty = threadIdx.y;
  int tid = ty * 16 + tx;
  double acc[4][4] = {};
  for (int c0 = 0; c0 < C; c0 += 16) {
    for (int rr = 0; rr < 4; ++rr) {
      int li = tid + rr * 256;
      int row = li >> 4, k = li & 15;
      int c = c0 + k;
      As[k][row] = (c < C) ? (double)Ab[(size_t)(i0 + row) * lda + c] : 0.0;
      Bs[k][row] = (c < C) ? (double)Ab[(size_t)(j0 + row) * lda + c] : 0.0;
    }
    __syncthreads();
#pragma unroll
    for (int k = 0; k < 16; ++k) {
      double a_[4], b_[4];
#pragma unroll
      for (int ii = 0; ii < 4; ++ii) a_[ii] = As[k][ty * 4 + ii];
#pragma unroll
      for (int jj = 0; jj < 4; ++jj) b_[jj] = Bs[k][jj * 16 + tx];
#pragma unroll
      for (int ii = 0; ii < 4; ++ii)
#pragma unroll
        for (int jj = 0; jj < 4; ++jj)
          acc[ii][jj] = fma(a_[ii], b_[jj], acc[ii][jj]);
    }
    __syncthreads();
  }
  for (int ii = 0; ii < 4; ++ii) {
    int i = i0 + ty * 4 + ii;
    for (int jj = 0; jj < 4; ++jj) {
      int j = j0 + jj * 16 + tx;
      double v = 2.0 * acc[ii][jj] - sqA[bg * NN + i] - sqA[bg * NN + j];
      D[((size_t)bl * NN + i) * MM + j] = v;
      T[jj * 16 + tx][ty * 4 + ii] = v;
    }
  }
  if (i0 != j0) {
    __syncthreads();
    for (int rr = 0; rr < 16; ++rr) {
      int li = tid + rr * 256;
      int jrow = li >> 6, il = li & 63;
      D[((size_t)bl * NN + j0 + jrow) * MM + i0 + il] = T[jrow][il];
    }
  }
}

// ------- top-20 per row, f64; grid (batch, rowblock) for XCD L2 affinity -------
__global__ __launch_bounds__(256) void k_topk(const double* __restrict__ D,
                                              int* __restrict__ idx, int b0) {
  int wave = threadIdx.x >> 6;
  int lane = threadIdx.x & 63;
  int bl = blockIdx.x;
  int row = blockIdx.y * 4 + wave;
  const double* rp = D + ((size_t)bl * NN + row) * MM;
  double v[16];
#pragma unroll
  for (int m = 0; m < 16; ++m) v[m] = rp[m * 64 + lane];
  int* op = idx + ((size_t)(b0 + bl) * NN + row) * KNN;
  for (int r = 0; r < KNN; ++r) {
    double bv = -INFINITY;
    int bj = MM;
#pragma unroll
    for (int m = 0; m < 16; ++m) {
      if (v[m] > bv) { bv = v[m]; bj = m * 64 + lane; }
    }
#pragma unroll
    for (int off = 32; off > 0; off >>= 1) {
      double ov = __shfl_xor(bv, off, 64);
      int oj = __shfl_xor(bj, off, 64);
      if (ov > bv || (ov == bv && oj < bj)) { bv = ov; bj = oj; }
    }
    if (bj < MM && lane == (bj & 63)) v[bj >> 6] = -INFINITY;
    if (lane == 0) op[r] = bj;
  }
}

// ------- per-point feature matmul (64x64 tile): batch = blockIdx.x (XCD affinity) -------
// mode 0: weff = w[o,c]; mode 1: weff = w[o,C+c] - w[o,c]
__global__ __launch_bounds__(256) void k_featmm(
    const float* __restrict__ src, int lds_, const float* __restrict__ w, int CW,
    float* __restrict__ out, int C, int O, int mode, int Np) {
  __shared__ float As[16][68];
  __shared__ float Ws[16][68];
  int b = blockIdx.x;
  int o0 = blockIdx.y * 64;
  int j0 = blockIdx.z * 64;
  int tx = threadIdx.x, ty = threadIdx.y;
  int tid = ty * 16 + tx;
  const float* Sb = src + (size_t)b * Np * lds_;
  float acc[4][4] = {};
  for (int c0 = 0; c0 < C; c0 += 16) {
    for (int r = 0; r < 4; ++r) {
      int li = tid + r * 256;
      int row = li >> 4, k = li & 15;
      int c = c0 + k;
      As[k][row] = (c < C) ? Sb[(size_t)(j0 + row) * lds_ + c] : 0.f;
      float wv = 0.f;
      if (c < C) {
        const float* wr = w + (size_t)(o0 + row) * CW;
        wv = mode == 0 ? wr[c] : (wr[C + c] - wr[c]);
      }
      Ws[k][row] = wv;
    }
    __syncthreads();
#pragma unroll
    for (int k = 0; k < 16; ++k) {
      float a_[4], b_[4];
#pragma unroll
      for (int ii = 0; ii < 4; ++ii) a_[ii] = As[k][ty * 4 + ii];
#pragma unroll
      for (int jj = 0; jj < 4; ++jj) b_[jj] = Ws[k][tx * 4 + jj];
#pragma unroll
      for (int ii = 0; ii < 4; ++ii)
#pragma unroll
        for (int jj = 0; jj < 4; ++jj)
          acc[ii][jj] = fmaf(a_[ii], b_[jj], acc[ii][jj]);
    }
    __syncthreads();
  }
  for (int ii = 0; ii < 4; ++ii) {
    int j = j0 + ty * 4 + ii;
    float4 v;
    float* vp = &v.x;
    for (int jj = 0; jj < 4; ++jj) vp[jj] = acc[ii][jj];
    *(float4*)&out[((size_t)b * Np + j) * O + o0 + tx * 4] = v;
  }
}

// ---- layer-5 GEMM: 128x128 tile, 8x8/thread, strided-o (conflict-free LDS) ----
__global__ __launch_bounds__(256) void k_gemm5(
    const float* __restrict__ src, const float* __restrict__ w, float* __restrict__ out) {
  __shared__ float As[16][132];
  __shared__ float Ws[16][132];
  int b = blockIdx.x;
  int j0 = blockIdx.y * 128;
  int o0 = blockIdx.z * 128;
  int tx = threadIdx.x, ty = threadIdx.y;
  int tid = ty * 16 + tx;
  const float* Sb = src + (size_t)b * NN * 512;
  float acc[8][8] = {};
  for (int c0 = 0; c0 < 512; c0 += 16) {
    for (int r = 0; r < 2; ++r) {
      int li = tid + r * 256;
      int row = li >> 2;
      int f = (li & 3) * 4;
      float4 av = *(const float4*)&Sb[(size_t)(j0 + row) * 512 + c0 + f];
      As[f + 0][row] = av.x;
      As[f + 1][row] = av.y;
      As[f + 2][row] = av.z;
      As[f + 3][row] = av.w;
      float4 wv = *(const float4*)&w[(size_t)(o0 + row) * 512 + c0 + f];
      Ws[f + 0][row] = wv.x;
      Ws[f + 1][row] = wv.y;
      Ws[f + 2][row] = wv.z;
      Ws[f + 3][row] = wv.w;
    }
    __syncthreads();
#pragma unroll
    for (int k = 0; k < 16; ++k) {
      float a_[8], b_[8];
#pragma unroll
      for (int ii = 0; ii < 8; ++ii) a_[ii] = As[k][ty * 8 + ii];
#pragma unroll
      for (int jj = 0; jj < 8; ++jj) b_[jj] = Ws[k][jj * 16 + tx];
#pragma unroll
      for (int ii = 0; ii < 8; ++ii)
#pragma unroll
        for (int jj = 0; jj < 8; ++jj)
          acc[ii][jj] = fmaf(a_[ii], b_[jj], acc[ii][jj]);
    }
    __syncthreads();
  }
  for (int ii = 0; ii < 8; ++ii) {
    int j = j0 + ty * 8 + ii;
    float* orow = &out[((size_t)b * NN + j) * 512 + o0 + tx];
#pragma unroll
    for (int jj = 0; jj < 8; ++jj) orow[jj * 16] = acc[ii][jj];
  }
}

// ------- fused gather: per (n,o) compute max_k y, accumulate BN stats; b = blockIdx.x -------
__global__ __launch_bounds__(256) void k_gather(
    const float* __restrict__ u, const float* __restrict__ t, const int* __restrict__ idx,
    double* __restrict__ stats, float* __restrict__ mx, int O, int srcNp) {
  __shared__ int lidx[16 * KNN];
  __shared__ double rs[256];
  __shared__ double rq[256];
  int b = blockIdx.x;
  int n0 = blockIdx.y * 16;
  int o0 = blockIdx.z * 64;
  int tid = threadIdx.x;
  int lane = tid & 63, nsl = tid >> 6;
  for (int w = tid; w < 16 * KNN; w += 256)
    lidx[w] = idx[((size_t)b * NN + n0) * KNN + w];
  __syncthreads();
  int oo = o0 + lane;
  double s1 = 0.0, s2 = 0.0;
  for (int ns = nsl; ns < 16; ns += 4) {
    size_t row = (size_t)b * NN + n0 + ns;
    float tv = t[row * O + oo];
    float mxv = -INFINITY, a1 = 0.f, a2 = 0.f;
#pragma unroll
    for (int k = 0; k < KNN; ++k) {
      int j = lidx[ns * KNN + k];
      float yv = u[((size_t)b * srcNp + j) * O + oo] + tv;
      mxv = fmaxf(mxv, yv);
      a1 += yv;
      a2 = fmaf(yv, yv, a2);
    }
    mx[row * O + oo] = mxv;
    s1 += (double)a1;
    s2 += (double)a2;
  }
  rs[tid] = s1;
  rq[tid] = s2;
  __syncthreads();
  if (tid < 64) {
    s1 = rs[tid] + rs[tid + 64] + rs[tid + 128] + rs[tid + 192];
    s2 = rq[tid] + rq[tid + 64] + rq[tid + 128] + rq[tid + 192];
    atomicAdd(&stats[o0 + tid], s1);
    atomicAdd(&stats[O + o0 + tid], s2);
  }
}

// ---------------- fold BN into per-channel scale/shift ----------------
__global__ void k_bnfin(const double* __restrict__ stats, const float* __restrict__ gamma,
                        const float* __restrict__ beta, float* __restrict__ sc,
                        int O, double cnt) {
  int o = threadIdx.x;
  if (o >= O) return;
  double mean = stats[o] / cnt;
  double var = stats[O + o] / cnt - mean * mean;
  if (var < 0.0) var = 0.0;
  double rstd = 1.0 / sqrt(var + 1e-5);
  float s = gamma[o] * (float)rstd;
  float c = beta[o] - (float)mean * s;
  sc[o] = s;
  sc[O + o] = c;
}

// ------- apply BN+lrelu to stored max, write cat slice. s<0 fallback: re-gather min -------
__global__ __launch_bounds__(256) void k_bnapply(
    const float* __restrict__ mx, const float* __restrict__ u, const float* __restrict__ t,
    const int* __restrict__ idx, const float* __restrict__ sc, float* __restrict__ cat,
    int coff, int O, int srcNp) {
  int i = blockIdx.x * 256 + threadIdx.x;
  int total = BB * NN * O;
  if (i >= total) return;
  int oo = i % O;
  int n = (i / O) % NN;
  int b = i / (O * NN);
  float s = sc[oo], c = sc[O + oo];
  float v;
  if (s >= 0.f) {
    v = mx[i];
  } else {  // monotone-decreasing transform needs min_k y (never hit with gamma=1)
    float tv = t[i];
    float mn = INFINITY;
    for (int k = 0; k < KNN; ++k) {
      int j = idx[((size_t)b * NN + n) * KNN + k];
      mn = fminf(mn, u[((size_t)b * srcNp + j) * O + oo] + tv);
    }
    v = mn;
  }
  float a = s * v + c;
  a = (a >= 0.f) ? a : NEG_SLOPE * a;
  cat[((size_t)b * NN + n) * 512 + coff + oo] = a;
}

// ------- layer 5 streaming stats over stored y5 (B,N,512) -------
__global__ __launch_bounds__(256) void k_stats512(
    const float* __restrict__ y5, double* __restrict__ stats) {
  int b = blockIdx.y;
  int n0 = blockIdx.x * 32;
  int tid = threadIdx.x;
  for (int part = 0; part < 2; ++part) {
    int oo = tid + part * 256;
    float a1 = 0.f, a2 = 0.f;
    for (int ns = 0; ns < 32; ++ns) {
      float v = y5[((size_t)b * NN + n0 + ns) * 512 + oo];
      a1 += v;
      a2 = fmaf(v, v, a2);
    }
    atomicAdd(&stats[oo], (double)a1);
    atomicAdd(&stats[512 + oo], (double)a2);
  }
}

// ------- layer 5 streaming finalize: BN+lrelu on stored y5, transpose, f32 store -------
__global__ __launch_bounds__(256) void k_final5b(
    const float* __restrict__ y5, const float* __restrict__ sc, float* __restrict__ out) {
  __shared__ float tile[64][65];
  int b = blockIdx.z;
  int n0 = blockIdx.x * 64;
  int o0 = blockIdx.y * 64;
  int tid = threadIdx.x;
  for (int r = 0; r < 16; ++r) {
    int li = tid + r * 256;
    int nl = li >> 6, ol = li & 63;
    float v = y5[((size_t)b * NN + n0 + nl) * 512 + o0 + ol];
    float a = sc[o0 + ol] * v + sc[512 + o0 + ol];
    a = (a >= 0.f) ? a : NEG_SLOPE * a;
    tile[nl][ol] = a;
  }
  __syncthreads();
  for (int r = 0; r < 16; ++r) {
    int li = tid + r * 256;
    int ol = li >> 6, nl = li & 63;
    out[((size_t)b * 512 + o0 + ol) * NN + n0 + nl] = tile[nl][ol];
  }
}

// ------- fallback layer 5 (CB<2): GEMM+stats recompute pass -------
__global__ __launch_bounds__(256) void k_mmstats(
    const float* __restrict__ src, const float* __restrict__ w,
    double* __restrict__ stats) {
  __shared__ float As[16][68];
  __shared__ float Ws[16][68];
  __shared__ float redS[16][64];
  __shared__ float redQ[16][64];
  int b = blockIdx.z;
  int j0 = blockIdx.y * 64;
  int o0 = blockIdx.x * 64;
  int tx = threadIdx.x, ty = threadIdx.y;
  int tid = ty * 16 + tx;
  const float* Sb = src + (size_t)b * NN * 512;
  float acc[4][4] = {};
  for (int c0 = 0; c0 < 512; c0 += 16) {
    for (int r = 0; r < 4; ++r) {
      int li = tid + r * 256;
      int row = li >> 4, k = li & 15;
      As[k][row] = Sb[(size_t)(j0 + row) * 512 + c0 + k];
      Ws[k][row] = w[(size_t)(o0 + row) * 512 + c0 + k];
    }
    __syncthreads();
#pragma unroll
    for (int k = 0; k < 16; ++k) {
      float a_[4], b_[4];
#pragma unroll
      for (int ii = 0; ii < 4; ++ii) a_[ii] = As[k][ty * 4 + ii];
#pragma unroll
      for (int jj = 0; jj < 4; ++jj) b_[jj] = Ws[k][tx * 4 + jj];
#pragma unroll
      for (int ii = 0; ii < 4; ++ii)
#pragma unroll
        for (int jj = 0; jj < 4; ++jj)
          acc[ii][jj] = fmaf(a_[ii], b_[jj], acc[ii][jj]);
    }
    __syncthreads();
  }
  for (int jj = 0; jj < 4; ++jj) {
    float s = 0.f, q = 0.f;
    for (int ii = 0; ii < 4; ++ii) { float v = acc[ii][jj]; s += v; q += v * v; }
    redS[ty][tx * 4 + jj] = s;
    redQ[ty][tx * 4 + jj] = q;
  }
  __syncthreads();
  if (tid < 64) {
    float s = 0.f, q = 0.f;
    for (int r = 0; r < 16; ++r) { s += redS[r][tid]; q += redQ[r][tid]; }
    atomicAdd(&stats[o0 + tid], (double)s);
    atomicAdd(&stats[512 + o0 + tid], (double)q);
  }
}

// ------- fallback layer 5 (CB<2): recompute GEMM, BN+lrelu, transposed store -------
__global__ __launch_bounds__(256) void k_final5(
    const float* __restrict__ src, const float* __restrict__ w,
    const float* __restrict__ sc, float* __restrict__ out) {
  __shared__ float As[16][68];
  __shared__ float Ws[16][68];
  __shared__ float tile[64][65];
  int b = blockIdx.z;
  int j0 = blockIdx.y * 64;
  int o0 = blockIdx.x * 64;
  int tx = threadIdx.x, ty = threadIdx.y;
  int tid = ty * 16 + tx;
  const float* Sb = src + (size_t)b * NN * 512;
  float acc[4][4] = {};
  for (int c0 = 0; c0 < 512; c0 += 16) {
    for (int r = 0; r < 4; ++r) {
      int li = tid + r * 256;
      int row = li >> 4, k = li & 15;
      As[k][row] = Sb[(size_t)(j0 + row) * 512 + c0 + k];
      Ws[k][row] = w[(size_t)(o0 + row) * 512 + c0 + k];
    }
    __syncthreads();
#pragma unroll
    for (int k = 0; k < 16; ++k) {
      float a_[4], b_[4];
#pragma unroll
      for (int ii = 0; ii < 4; ++ii) a_[ii] = As[k][ty * 4 + ii];
#pragma unroll
      for (int jj = 0; jj < 4; ++jj) b_[jj] = Ws[k][tx * 4 + jj];
#pragma unroll
      for (int ii = 0; ii < 4; ++ii)
#pragma unroll
        for (int jj = 0; jj < 4; ++jj)
          acc[ii][jj] = fmaf(a_[ii], b_[jj], acc[ii][jj]);
    }
    __syncthreads();
  }
  for (int ii = 0; ii < 4; ++ii)
    for (int jj = 0; jj < 4; ++jj) {
      int nl = ty * 4 + ii, ol = tx * 4 + jj;
      float a = sc[o0 + ol] * acc[ii][jj] + sc[512 + o0 + ol];
      a = (a >= 0.f) ? a : NEG_SLOPE * a;
      tile[nl][ol] = a;
    }
  __syncthreads();
  for (int r = 0; r < 16; ++r) {
    int li = tid + r * 256;
    int ol = li >> 6, nl = li & 63;
    out[((size_t)b * 512 + o0 + ol) * NN + j0 + nl] = tile[nl][ol];
  }
}

// =====================================================================================
// r9: conflict-free strided LDS fragment mapping (j/o = jj*16+tx) in gram2/gemm5/gram_sym
// (r8 had 8-way f64 bank conflicts: 1.57e7/dispatch); fused L1 knn (C=3, no DD);
// XCD-affine topk grid. All math bitwise-identical to r8 (same FMA chains).
extern "C" void kernel_launch(void* const* d_in, const int* in_sizes, int n_in,
                              void* d_out, int out_size, void* d_ws, size_t ws_size,
                              hipStream_t stream) {
  const float* x = (const float*)d_in[0];
  const float* y = (const float*)d_in[1];
  const float* w1 = (const float*)d_in[2];
  const float* w2 = (const float*)d_in[3];
  const float* w3 = (const float*)d_in[4];
  const float* w4 = (const float*)d_in[5];
  const float* w5 = (const float*)d_in[6];
  const float* g1 = (const float*)d_in[7];
  const float* b1 = (const float*)d_in[8];
  const float* g2 = (const float*)d_in[9];
  const float* b2 = (const float*)d_in[10];
  const float* g3 = (const float*)d_in[11];
  const float* b3 = (const float*)d_in[12];
  const float* g4 = (const float*)d_in[13];
  const float* b4 = (const float*)d_in[14];
  const float* g5 = (const float*)d_in[15];
  const float* b5 = (const float*)d_in[16];

  char* base = (char*)d_ws;
  size_t off = 0;
  auto alloc = [&](size_t bytes) -> char* {
    char* p = base + off;
    off += (bytes + 255) & ~(size_t)255;
    return p;
  };
  double* st = (double*)alloc(1024 * 8);
  float* sc  = (float*)alloc(1024 * 4);
  double* sq  = (double*)alloc((size_t)BB * NN * 8);
  double* rnx = (double*)alloc((size_t)BB * NN * 8);
  double* rny = (double*)alloc((size_t)BB * MM * 8);
  int*   idxb = (int*)alloc((size_t)BB * NN * KNN * 4);
  float* xs3 = (float*)alloc((size_t)BB * NN * 3 * 4);
  float* ys  = (float*)alloc((size_t)BB * MM * 128 * 4);
  float* cat = (float*)alloc((size_t)BB * NN * 512 * 4);
  size_t ddBatchBytes = (size_t)NN * MM * 8;  // 8 MB per batch (f64)
  size_t avail = (ws_size > off) ? (ws_size - off) : 0;
  int CB = (int)(avail / ddBatchBytes);
  if (CB < 1) CB = 1;
  if (CB > BB) CB = BB;
  char*  U   = alloc((size_t)CB * ddBatchBytes);
  double* DD = (double*)U;                     // dist/simi chunk (f64), dead after topk
  float* tt  = (float*)U;                      // center term (f32, <=8MB), after DD dead
  float* y5  = (float*)U;                      // layer-5 pre-BN (16MB, needs CB>=2)
  float* uu  = (float*)d_out;                  // source term (<=8MB)
  float* mx  = (float*)d_out + (size_t)2 * 1024 * 1024;  // max_k y (<=8MB)
  float* outp = (float*)d_out;

  const dim3 blk2(16, 16);
  const double cntE = (double)BB * NN * KNN;

  // knn: sym=1 -> triangular symmetric euclid gram (A==B); else general 128-tile MODE
  auto knn = [&](const float* A, int lda, const float* Bm, int ldb,
                 const double* sa, const double* sb, int C, int mode, int sym) {
    for (int b0 = 0; b0 < BB; b0 += CB) {
      int cb = (BB - b0 < CB) ? (BB - b0) : CB;
      if (sym) {
        k_gram_sym<<<dim3(cb, 136), blk2, 0, stream>>>(A, lda, sa, DD, C, b0);
      } else {
        dim3 g(cb, MM / 128, NN / 128);
        if (mode == 1) k_gram2<1><<<g, blk2, 0, stream>>>(A, lda, Bm, ldb, sa, sb, DD, C, b0);
        else           k_gram2<2><<<g, blk2, 0, stream>>>(A, lda, Bm, ldb, sa, sb, DD, C, b0);
      }
      k_topk<<<dim3(cb, 256), 256, 0, stream>>>(DD, idxb, b0);
    }
  };

  auto edge_layer = [&](const float* ctr, int ldc, const float* src, int ldsrc, int srcNp,
                        const float* w, int CW, const float* g, const float* bb,
                        int C, int O, int coff) {
    k_featmm<<<dim3(8, O / 64, 16), blk2, 0, stream>>>(src, ldsrc, w, CW, uu, C, O, 0, srcNp);
    k_featmm<<<dim3(8, O / 64, 16), blk2, 0, stream>>>(ctr, ldc, w, CW, tt, C, O, 1, NN);
    hipMemsetAsync(st, 0, 1024 * 8, stream);
    k_gather<<<dim3(BB, NN / 16, O / 64), 256, 0, stream>>>(uu, tt, idxb, st, mx, O, srcNp);
    k_bnfin<<<1, O, 0, stream>>>(st, g, bb, sc, O, cntE);
    k_bnapply<<<(BB * NN * O + 255) / 256, 256, 0, stream>>>(mx, uu, tt, idxb, sc, cat,
                                                             coff, O, srcNp);
  };

  // ---- input transposes ----
  k_transpose<<<96, 256, 0, stream>>>(x, xs3, 3, NN);
  k_transpose<<<2048, 256, 0, stream>>>(y, ys, 128, MM);

  // ---- layer 1: C=3, O=64 (fused knn, no DD) ----
  k_rowsq<0><<<32, 256, 0, stream>>>(xs3, 3, 3, sq);
  k_knn3<<<dim3(BB, 256), 256, 0, stream>>>(xs3, sq, idxb);
  edge_layer(xs3, 3, xs3, 3, NN, w1, 6, g1, b1, 3, 64, 0);

  // ---- layer 2: x1 = cat[:,0:64], C=64, O=64 ----
  k_rowsq<0><<<32, 256, 0, stream>>>(cat, 512, 64, sq);
  knn(cat, 512, cat, 512, sq, sq, 64, 1, 1);
  edge_layer(cat, 512, cat, 512, NN, w2, 128, g2, b2, 64, 64, 64);

  // ---- layer 3: x2 = cat[:,64:128], C=64, O=128 ----
  k_rowsq<0><<<32, 256, 0, stream>>>(cat + 64, 512, 64, sq);
  knn(cat + 64, 512, cat + 64, 512, sq, sq, 64, 1, 1);
  edge_layer(cat + 64, 512, cat + 64, 512, NN, w3, 128, g3, b3, 64, 128, 128);

  // ---- layer 4 (IA): x3 = cat[:,128:256], src = y (cosine knn), C=128, O=256 ----
  k_rowsq<1><<<32, 256, 0, stream>>>(cat + 128, 512, 128, rnx);
  k_rowsq<1><<<32, 256, 0, stream>>>(ys, 128, 128, rny);
  knn(cat + 128, 512, ys, 128, rnx, rny, 128, 2, 0);
  edge_layer(cat + 128, 512, ys, 128, MM, w4, 256, g4, b4, 128, 256, 256);

  // ---- layer 5: GEMM (C=512,O=512) -> y5, BN over (B,N), lrelu, transposed out ----
  hipMemsetAsync(st, 0, 1024 * 8, stream);
  if (CB >= 2) {
    k_gemm5<<<dim3(8, 8, 4), blk2, 0, stream>>>(cat, w5, y5);
    k_stats512<<<dim3(32, 8), 256, 0, stream>>>(y5, st);
    k_bnfin<<<1, 512, 0, stream>>>(st, g5, b5, sc, 512, (double)(BB * NN));
    k_final5b<<<dim3(16, 8, 8), 256, 0, stream>>>(y5, sc, outp);
  } else {
    k_mmstats<<<dim3(8, 16, 8), blk2, 0, stream>>>(cat, w5, st);
    k_bnfin<<<1, 512, 0, stream>>>(st, g5, b5, sc, 512, (double)(BB * NN));
    k_final5<<<dim3(8, 16, 8), blk2, 0, stream>>>(cat, w5, sc, outp);
  }
}

// Round 10
// 773.128 us; speedup vs baseline: 1.4887x; 1.0111x over previous
//
#include <hip/hip_runtime.h>
#include <hip/hip_bf16.h>

#define KNN 20
#define NEG_SLOPE 0.2f

constexpr int BB = 8;
constexpr int NN = 1024;
constexpr int MM = 1024;

// ---------------- transpose f32: (B,C,Np) -> (B,Np,C) ----------------
__global__ __launch_bounds__(256) void k_transpose(
    const float* __restrict__ in, float* __restrict__ out, int C, int Np) {
  int total = BB * C * Np;
  for (int t = blockIdx.x * 256 + threadIdx.x; t < total; t += gridDim.x * 256) {
    int c = t % C;
    int n = (t / C) % Np;
    int b = t / (C * Np);
    out[t] = in[((size_t)b * C + c) * Np + n];
  }
}

// ------- per-point squared norm (RECIP=0) or reciprocal norm (RECIP=1), f64 out -------
template <int RECIP>
__global__ __launch_bounds__(256) void k_rowsq(
    const float* __restrict__ A, int ld, int C, double* __restrict__ sq) {
  int p = blockIdx.x * 256 + threadIdx.x;
  if (p >= BB * NN) return;
  const float* row = A + (size_t)p * ld;
  double s = 0.0;
  for (int c = 0; c < C; ++c) { double v = (double)row[c]; s += v * v; }
  if (RECIP) {
    sq[p] = 1.0 / fmax(sqrt(s), 1e-12);
  } else {
    sq[p] = s;
  }
}

// ---- fused L1 knn (C=3): all points in LDS, f64 distances in-register, topk direct ----
__global__ __launch_bounds__(256) void k_knn3(
    const float* __restrict__ xs3, const double* __restrict__ sq, int* __restrict__ idx) {
  __shared__ float P[NN * 3];
  int b = blockIdx.x;
  const float* Xb = xs3 + (size_t)b * NN * 3;
  int tid = threadIdx.x;
  for (int t = tid; t < NN * 3; t += 256) P[t] = Xb[t];
  __syncthreads();
  int wave = tid >> 6, lane = tid & 63;
  int i = blockIdx.y * 4 + wave;
  double xi = (double)P[i * 3], yi = (double)P[i * 3 + 1], zi = (double)P[i * 3 + 2];
  double sqi = sq[b * NN + i];
  double v[16];
#pragma unroll
  for (int m = 0; m < 16; ++m) {
    int j = m * 64 + lane;
    double d = fma(xi, (double)P[j * 3], 0.0);
    d = fma(yi, (double)P[j * 3 + 1], d);
    d = fma(zi, (double)P[j * 3 + 2], d);
    v[m] = 2.0 * d - sqi - sq[b * NN + j];
  }
  int* op = idx + ((size_t)b * NN + i) * KNN;
  for (int r = 0; r < KNN; ++r) {
    double bv = -INFINITY;
    int bj = MM;
#pragma unroll
    for (int m = 0; m < 16; ++m) {
      if (v[m] > bv) { bv = v[m]; bj = m * 64 + lane; }
    }
#pragma unroll
    for (int off = 32; off > 0; off >>= 1) {
      double ov = __shfl_xor(bv, off, 64);
      int oj = __shfl_xor(bj, off, 64);
      if (ov > bv || (ov == bv && oj < bj)) { bv = ov; bj = oj; }
    }
    if (bj < MM && lane == (bj & 63)) v[bj >> 6] = -INFINITY;
    if (lane == 0) op[r] = bj;
  }
}

// ---- f64 gram: 128(i)x64(j) tiles, 8x4/thread, conflict-free strided-j, 1024 blocks ----
// MODE 1: D = 2*dot - sqA_i - sqB_j ; MODE 2: D = dot * rnA_i * rnB_j
template <int MODE>
__global__ __launch_bounds__(256) void k_gram2(
    const float* __restrict__ A, int lda, const float* __restrict__ Bm, int ldb,
    const double* __restrict__ sqA, const double* __restrict__ sqB,
    double* __restrict__ D, int C, int b0) {
  __shared__ double As[16][136];
  __shared__ double Bs[16][72];
  int bg = b0 + blockIdx.x;
  int bl = blockIdx.x;
  int j0 = blockIdx.y * 64;
  int i0 = blockIdx.z * 128;
  const float* Ab = A + (size_t)bg * NN * lda;
  const float* Bb = Bm + (size_t)bg * MM * ldb;
  int tx = threadIdx.x, ty = threadIdx.y;
  int tid = ty * 16 + tx;
  double acc[8][4] = {};
  for (int c0 = 0; c0 < C; c0 += 16) {
    for (int r = 0; r < 2; ++r) {
      int li = tid + r * 256;
      int row = li >> 2;
      int f = (li & 3) * 4;
      float4 av = *(const float4*)&Ab[(size_t)(i0 + row) * lda + c0 + f];
      As[f + 0][row] = (double)av.x;
      As[f + 1][row] = (double)av.y;
      As[f + 2][row] = (double)av.z;
      As[f + 3][row] = (double)av.w;
    }
    {
      int row = tid >> 2;
      int f = (tid & 3) * 4;
      float4 bv = *(const float4*)&Bb[(size_t)(j0 + row) * ldb + c0 + f];
      Bs[f + 0][row] = (double)bv.x;
      Bs[f + 1][row] = (double)bv.y;
      Bs[f + 2][row] = (double)bv.z;
      Bs[f + 3][row] = (double)bv.w;
    }
    __syncthreads();
#pragma unroll
    for (int k = 0; k < 16; ++k) {
      double a_[8], b_[4];
#pragma unroll
      for (int ii = 0; ii < 8; ++ii) a_[ii] = As[k][ty * 8 + ii];
#pragma unroll
      for (int jj = 0; jj < 4; ++jj) b_[jj] = Bs[k][jj * 16 + tx];
#pragma unroll
      for (int ii = 0; ii < 8; ++ii)
#pragma unroll
        for (int jj = 0; jj < 4; ++jj)
          acc[ii][jj] = fma(a_[ii], b_[jj], acc[ii][jj]);
    }
    __syncthreads();
  }
  for (int ii = 0; ii < 8; ++ii) {
    int i = i0 + ty * 8 + ii;
    for (int jj = 0; jj < 4; ++jj) {
      int j = j0 + jj * 16 + tx;
      double r = acc[ii][jj];
      if (MODE == 1) r = 2.0 * r - sqA[bg * NN + i] - sqB[bg * NN + j];
      if (MODE == 2) r = r * sqA[bg * NN + i] * sqB[bg * NN + j];
      D[((size_t)bl * NN + i) * MM + j] = r;
    }
  }
}

// ------- symmetric euclidean gram (A==B): triangular blocks, strided-j mapping -------
__global__ __launch_bounds__(256) void k_gram_sym(
    const float* __restrict__ A, int lda, const double* __restrict__ sqA,
    double* __restrict__ D, int C, int b0) {
  __shared__ double As[16][68];
  __shared__ double Bs[16][68];
  __shared__ double T[64][65];
  int p = blockIdx.y;  // 0..135 triangular pair index
  int r = (int)((sqrtf(8.f * p + 1.f) - 1.f) * 0.5f);
  while ((r + 1) * (r + 2) / 2 <= p) ++r;
  while (r * (r + 1) / 2 > p) --r;
  int cc = p - r * (r + 1) / 2;
  int i0 = r * 64, j0 = cc * 64;
  int bg = b0 + blockIdx.x;
  int bl = blockIdx.x;
  const float* Ab = A + (size_t)bg * NN * lda;
  int tx = threadIdx.x, ty = threadIdx.y;
  int tid = ty * 16 + tx;
  double acc[4][4] = {};
  for (int c0 = 0; c0 < C; c0 += 16) {
    for (int rr = 0; rr < 4; ++rr) {
      int li = tid + rr * 256;
      int row = li >> 4, k = li & 15;
      int c = c0 + k;
      As[k][row] = (c < C) ? (double)Ab[(size_t)(i0 + row) * lda + c] : 0.0;
      Bs[k][row] = (c < C) ? (double)Ab[(size_t)(j0 + row) * lda + c] : 0.0;
    }
    __syncthreads();
#pragma unroll
    for (int k = 0; k < 16; ++k) {
      double a_[4], b_[4];
#pragma unroll
      for (int ii = 0; ii < 4; ++ii) a_[ii] = As[k][ty * 4 + ii];
#pragma unroll
      for (int jj = 0; jj < 4; ++jj) b_[jj] = Bs[k][jj * 16 + tx];
#pragma unroll
      for (int ii = 0; ii < 4; ++ii)
#pragma unroll
        for (int jj = 0; jj < 4; ++jj)
          acc[ii][jj] = fma(a_[ii], b_[jj], acc[ii][jj]);
    }
    __syncthreads();
  }
  for (int ii = 0; ii < 4; ++ii) {
    int i = i0 + ty * 4 + ii;
    for (int jj = 0; jj < 4; ++jj) {
      int j = j0 + jj * 16 + tx;
      double v = 2.0 * acc[ii][jj] - sqA[bg * NN + i] - sqA[bg * NN + j];
      D[((size_t)bl * NN + i) * MM + j] = v;
      T[jj * 16 + tx][ty * 4 + ii] = v;
    }
  }
  if (i0 != j0) {
    __syncthreads();
    for (int rr = 0; rr < 16; ++rr) {
      int li = tid + rr * 256;
      int jrow = li >> 6, il = li & 63;
      D[((size_t)bl * NN + j0 + jrow) * MM + i0 + il] = T[jrow][il];
    }
  }
}

// ------- top-20 per row, f64; grid (batch, rowblock) for XCD L2 affinity -------
__global__ __launch_bounds__(256) void k_topk(const double* __restrict__ D,
                                              int* __restrict__ idx, int b0) {
  int wave = threadIdx.x >> 6;
  int lane = threadIdx.x & 63;
  int bl = blockIdx.x;
  int row = blockIdx.y * 4 + wave;
  const double* rp = D + ((size_t)bl * NN + row) * MM;
  double v[16];
#pragma unroll
  for (int m = 0; m < 16; ++m) v[m] = rp[m * 64 + lane];
  int* op = idx + ((size_t)(b0 + bl) * NN + row) * KNN;
  for (int r = 0; r < KNN; ++r) {
    double bv = -INFINITY;
    int bj = MM;
#pragma unroll
    for (int m = 0; m < 16; ++m) {
      if (v[m] > bv) { bv = v[m]; bj = m * 64 + lane; }
    }
#pragma unroll
    for (int off = 32; off > 0; off >>= 1) {
      double ov = __shfl_xor(bv, off, 64);
      int oj = __shfl_xor(bj, off, 64);
      if (ov > bv || (ov == bv && oj < bj)) { bv = ov; bj = oj; }
    }
    if (bj < MM && lane == (bj & 63)) v[bj >> 6] = -INFINITY;
    if (lane == 0) op[r] = bj;
  }
}

// ------- per-point feature matmul (64x64 tile): batch = blockIdx.x (XCD affinity) -------
// mode 0: weff = w[o,c]; mode 1: weff = w[o,C+c] - w[o,c]
__global__ __launch_bounds__(256) void k_featmm(
    const float* __restrict__ src, int lds_, const float* __restrict__ w, int CW,
    float* __restrict__ out, int C, int O, int mode, int Np) {
  __shared__ float As[16][68];
  __shared__ float Ws[16][68];
  int b = blockIdx.x;
  int o0 = blockIdx.y * 64;
  int j0 = blockIdx.z * 64;
  int tx = threadIdx.x, ty = threadIdx.y;
  int tid = ty * 16 + tx;
  const float* Sb = src + (size_t)b * Np * lds_;
  float acc[4][4] = {};
  for (int c0 = 0; c0 < C; c0 += 16) {
    for (int r = 0; r < 4; ++r) {
      int li = tid + r * 256;
      int row = li >> 4, k = li & 15;
      int c = c0 + k;
      As[k][row] = (c < C) ? Sb[(size_t)(j0 + row) * lds_ + c] : 0.f;
      float wv = 0.f;
      if (c < C) {
        const float* wr = w + (size_t)(o0 + row) * CW;
        wv = mode == 0 ? wr[c] : (wr[C + c] - wr[c]);
      }
      Ws[k][row] = wv;
    }
    __syncthreads();
#pragma unroll
    for (int k = 0; k < 16; ++k) {
      float a_[4], b_[4];
#pragma unroll
      for (int ii = 0; ii < 4; ++ii) a_[ii] = As[k][ty * 4 + ii];
#pragma unroll
      for (int jj = 0; jj < 4; ++jj) b_[jj] = Ws[k][tx * 4 + jj];
#pragma unroll
      for (int ii = 0; ii < 4; ++ii)
#pragma unroll
        for (int jj = 0; jj < 4; ++jj)
          acc[ii][jj] = fmaf(a_[ii], b_[jj], acc[ii][jj]);
    }
    __syncthreads();
  }
  for (int ii = 0; ii < 4; ++ii) {
    int j = j0 + ty * 4 + ii;
    float4 v;
    float* vp = &v.x;
    for (int jj = 0; jj < 4; ++jj) vp[jj] = acc[ii][jj];
    *(float4*)&out[((size_t)b * Np + j) * O + o0 + tx * 4] = v;
  }
}

// ---- layer-5 GEMM: 128(j)x64(o) tiles, 8x4/thread, strided-o, 512 blocks ----
__global__ __launch_bounds__(256) void k_gemm5(
    const float* __restrict__ src, const float* __restrict__ w, float* __restrict__ out) {
  __shared__ float As[16][132];
  __shared__ float Ws[16][68];
  int b = blockIdx.x;
  int j0 = blockIdx.y * 128;
  int o0 = blockIdx.z * 64;
  int tx = threadIdx.x, ty = threadIdx.y;
  int tid = ty * 16 + tx;
  const float* Sb = src + (size_t)b * NN * 512;
  float acc[8][4] = {};
  for (int c0 = 0; c0 < 512; c0 += 16) {
    for (int r = 0; r < 2; ++r) {
      int li = tid + r * 256;
      int row = li >> 2;
      int f = (li & 3) * 4;
      float4 av = *(const float4*)&Sb[(size_t)(j0 + row) * 512 + c0 + f];
      As[f + 0][row] = av.x;
      As[f + 1][row] = av.y;
      As[f + 2][row] = av.z;
      As[f + 3][row] = av.w;
    }
    {
      int row = tid >> 2;
      int f = (tid & 3) * 4;
      float4 wv = *(const float4*)&w[(size_t)(o0 + row) * 512 + c0 + f];
      Ws[f + 0][row] = wv.x;
      Ws[f + 1][row] = wv.y;
      Ws[f + 2][row] = wv.z;
      Ws[f + 3][row] = wv.w;
    }
    __syncthreads();
#pragma unroll
    for (int k = 0; k < 16; ++k) {
      float a_[8], b_[4];
#pragma unroll
      for (int ii = 0; ii < 8; ++ii) a_[ii] = As[k][ty * 8 + ii];
#pragma unroll
      for (int jj = 0; jj < 4; ++jj) b_[jj] = Ws[k][jj * 16 + tx];
#pragma unroll
      for (int ii = 0; ii < 8; ++ii)
#pragma unroll
        for (int jj = 0; jj < 4; ++jj)
          acc[ii][jj] = fmaf(a_[ii], b_[jj], acc[ii][jj]);
    }
    __syncthreads();
  }
  for (int ii = 0; ii < 8; ++ii) {
    int j = j0 + ty * 8 + ii;
    float* orow = &out[((size_t)b * NN + j) * 512 + o0 + tx];
#pragma unroll
    for (int jj = 0; jj < 4; ++jj) orow[jj * 16] = acc[ii][jj];
  }
}

// ------- fused gather: per (n,o) compute max_k y, accumulate BN stats; b = blockIdx.x -------
__global__ __launch_bounds__(256) void k_gather(
    const float* __restrict__ u, const float* __restrict__ t, const int* __restrict__ idx,
    double* __restrict__ stats, float* __restrict__ mx, int O, int srcNp) {
  __shared__ int lidx[16 * KNN];
  __shared__ double rs[256];
  __shared__ double rq[256];
  int b = blockIdx.x;
  int n0 = blockIdx.y * 16;
  int o0 = blockIdx.z * 64;
  int tid = threadIdx.x;
  int lane = tid & 63, nsl = tid >> 6;
  for (int w = tid; w < 16 * KNN; w += 256)
    lidx[w] = idx[((size_t)b * NN + n0) * KNN + w];
  __syncthreads();
  int oo = o0 + lane;
  double s1 = 0.0, s2 = 0.0;
  for (int ns = nsl; ns < 16; ns += 4) {
    size_t row = (size_t)b * NN + n0 + ns;
    float tv = t[row * O + oo];
    float mxv = -INFINITY, a1 = 0.f, a2 = 0.f;
#pragma unroll
    for (int k = 0; k < KNN; ++k) {
      int j = lidx[ns * KNN + k];
      float yv = u[((size_t)b * srcNp + j) * O + oo] + tv;
      mxv = fmaxf(mxv, yv);
      a1 += yv;
      a2 = fmaf(yv, yv, a2);
    }
    mx[row * O + oo] = mxv;
    s1 += (double)a1;
    s2 += (double)a2;
  }
  rs[tid] = s1;
  rq[tid] = s2;
  __syncthreads();
  if (tid < 64) {
    s1 = rs[tid] + rs[tid + 64] + rs[tid + 128] + rs[tid + 192];
    s2 = rq[tid] + rq[tid + 64] + rq[tid + 128] + rq[tid + 192];
    atomicAdd(&stats[o0 + tid], s1);
    atomicAdd(&stats[O + o0 + tid], s2);
  }
}

// ---------------- fold BN into per-channel scale/shift ----------------
__global__ void k_bnfin(const double* __restrict__ stats, const float* __restrict__ gamma,
                        const float* __restrict__ beta, float* __restrict__ sc,
                        int O, double cnt) {
  int o = threadIdx.x;
  if (o >= O) return;
  double mean = stats[o] / cnt;
  double var = stats[O + o] / cnt - mean * mean;
  if (var < 0.0) var = 0.0;
  double rstd = 1.0 / sqrt(var + 1e-5);
  float s = gamma[o] * (float)rstd;
  float c = beta[o] - (float)mean * s;
  sc[o] = s;
  sc[O + o] = c;
}

// ------- apply BN+lrelu to stored max, write cat slice. s<0 fallback: re-gather min -------
__global__ __launch_bounds__(256) void k_bnapply(
    const float* __restrict__ mx, const float* __restrict__ u, const float* __restrict__ t,
    const int* __restrict__ idx, const float* __restrict__ sc, float* __restrict__ cat,
    int coff, int O, int srcNp) {
  int i = blockIdx.x * 256 + threadIdx.x;
  int total = BB * NN * O;
  if (i >= total) return;
  int oo = i % O;
  int n = (i / O) % NN;
  int b = i / (O * NN);
  float s = sc[oo], c = sc[O + oo];
  float v;
  if (s >= 0.f) {
    v = mx[i];
  } else {  // monotone-decreasing transform needs min_k y (never hit with gamma=1)
    float tv = t[i];
    float mn = INFINITY;
    for (int k = 0; k < KNN; ++k) {
      int j = idx[((size_t)b * NN + n) * KNN + k];
      mn = fminf(mn, u[((size_t)b * srcNp + j) * O + oo] + tv);
    }
    v = mn;
  }
  float a = s * v + c;
  a = (a >= 0.f) ? a : NEG_SLOPE * a;
  cat[((size_t)b * NN + n) * 512 + coff + oo] = a;
}

// ------- layer 5 streaming stats over stored y5 (B,N,512) -------
__global__ __launch_bounds__(256) void k_stats512(
    const float* __restrict__ y5, double* __restrict__ stats) {
  int b = blockIdx.y;
  int n0 = blockIdx.x * 32;
  int tid = threadIdx.x;
  for (int part = 0; part < 2; ++part) {
    int oo = tid + part * 256;
    float a1 = 0.f, a2 = 0.f;
    for (int ns = 0; ns < 32; ++ns) {
      float v = y5[((size_t)b * NN + n0 + ns) * 512 + oo];
      a1 += v;
      a2 = fmaf(v, v, a2);
    }
    atomicAdd(&stats[oo], (double)a1);
    atomicAdd(&stats[512 + oo], (double)a2);
  }
}

// ------- layer 5 streaming finalize: BN+lrelu on stored y5, transpose, f32 store -------
__global__ __launch_bounds__(256) void k_final5b(
    const float* __restrict__ y5, const float* __restrict__ sc, float* __restrict__ out) {
  __shared__ float tile[64][65];
  int b = blockIdx.z;
  int n0 = blockIdx.x * 64;
  int o0 = blockIdx.y * 64;
  int tid = threadIdx.x;
  for (int r = 0; r < 16; ++r) {
    int li = tid + r * 256;
    int nl = li >> 6, ol = li & 63;
    float v = y5[((size_t)b * NN + n0 + nl) * 512 + o0 + ol];
    float a = sc[o0 + ol] * v + sc[512 + o0 + ol];
    a = (a >= 0.f) ? a : NEG_SLOPE * a;
    tile[nl][ol] = a;
  }
  __syncthreads();
  for (int r = 0; r < 16; ++r) {
    int li = tid + r * 256;
    int ol = li >> 6, nl = li & 63;
    out[((size_t)b * 512 + o0 + ol) * NN + n0 + nl] = tile[nl][ol];
  }
}

// ------- fallback layer 5 (CB<2): GEMM+stats recompute pass -------
__global__ __launch_bounds__(256) void k_mmstats(
    const float* __restrict__ src, const float* __restrict__ w,
    double* __restrict__ stats) {
  __shared__ float As[16][68];
  __shared__ float Ws[16][68];
  __shared__ float redS[16][64];
  __shared__ float redQ[16][64];
  int b = blockIdx.z;
  int j0 = blockIdx.y * 64;
  int o0 = blockIdx.x * 64;
  int tx = threadIdx.x, ty = threadIdx.y;
  int tid = ty * 16 + tx;
  const float* Sb = src + (size_t)b * NN * 512;
  float acc[4][4] = {};
  for (int c0 = 0; c0 < 512; c0 += 16) {
    for (int r = 0; r < 4; ++r) {
      int li = tid + r * 256;
      int row = li >> 4, k = li & 15;
      As[k][row] = Sb[(size_t)(j0 + row) * 512 + c0 + k];
      Ws[k][row] = w[(size_t)(o0 + row) * 512 + c0 + k];
    }
    __syncthreads();
#pragma unroll
    for (int k = 0; k < 16; ++k) {
      float a_[4], b_[4];
#pragma unroll
      for (int ii = 0; ii < 4; ++ii) a_[ii] = As[k][ty * 4 + ii];
#pragma unroll
      for (int jj = 0; jj < 4; ++jj) b_[jj] = Ws[k][tx * 4 + jj];
#pragma unroll
      for (int ii = 0; ii < 4; ++ii)
#pragma unroll
        for (int jj = 0; jj < 4; ++jj)
          acc[ii][jj] = fmaf(a_[ii], b_[jj], acc[ii][jj]);
    }
    __syncthreads();
  }
  for (int jj = 0; jj < 4; ++jj) {
    float s = 0.f, q = 0.f;
    for (int ii = 0; ii < 4; ++ii) { float v = acc[ii][jj]; s += v; q += v * v; }
    redS[ty][tx * 4 + jj] = s;
    redQ[ty][tx * 4 + jj] = q;
  }
  __syncthreads();
  if (tid < 64) {
    float s = 0.f, q = 0.f;
    for (int r = 0; r < 16; ++r) { s += redS[r][tid]; q += redQ[r][tid]; }
    atomicAdd(&stats[o0 + tid], (double)s);
    atomicAdd(&stats[512 + o0 + tid], (double)q);
  }
}

// ------- fallback layer 5 (CB<2): recompute GEMM, BN+lrelu, transposed store -------
__global__ __launch_bounds__(256) void k_final5(
    const float* __restrict__ src, const float* __restrict__ w,
    const float* __restrict__ sc, float* __restrict__ out) {
  __shared__ float As[16][68];
  __shared__ float Ws[16][68];
  __shared__ float tile[64][65];
  int b = blockIdx.z;
  int j0 = blockIdx.y * 64;
  int o0 = blockIdx.x * 64;
  int tx = threadIdx.x, ty = threadIdx.y;
  int tid = ty * 16 + tx;
  const float* Sb = src + (size_t)b * NN * 512;
  float acc[4][4] = {};
  for (int c0 = 0; c0 < 512; c0 += 16) {
    for (int r = 0; r < 4; ++r) {
      int li = tid + r * 256;
      int row = li >> 4, k = li & 15;
      As[k][row] = Sb[(size_t)(j0 + row) * 512 + c0 + k];
      Ws[k][row] = w[(size_t)(o0 + row) * 512 + c0 + k];
    }
    __syncthreads();
#pragma unroll
    for (int k = 0; k < 16; ++k) {
      float a_[4], b_[4];
#pragma unroll
      for (int ii = 0; ii < 4; ++ii) a_[ii] = As[k][ty * 4 + ii];
#pragma unroll
      for (int jj = 0; jj < 4; ++jj) b_[jj] = Ws[k][tx * 4 + jj];
#pragma unroll
      for (int ii = 0; ii < 4; ++ii)
#pragma unroll
        for (int jj = 0; jj < 4; ++jj)
          acc[ii][jj] = fmaf(a_[ii], b_[jj], acc[ii][jj]);
    }
    __syncthreads();
  }
  for (int ii = 0; ii < 4; ++ii)
    for (int jj = 0; jj < 4; ++jj) {
      int nl = ty * 4 + ii, ol = tx * 4 + jj;
      float a = sc[o0 + ol] * acc[ii][jj] + sc[512 + o0 + ol];
      a = (a >= 0.f) ? a : NEG_SLOPE * a;
      tile[nl][ol] = a;
    }
  __syncthreads();
  for (int r = 0; r < 16; ++r) {
    int li = tid + r * 256;
    int ol = li >> 6, nl = li & 63;
    out[((size_t)b * 512 + o0 + ol) * NN + j0 + nl] = tile[nl][ol];
  }
}

// =====================================================================================
// r10: occupancy fix for the two big GEMM-shaped kernels (r9 showed k_gemm5 at 1
// block/CU, VALUBusy 38%): k_gemm5 -> 128x64 tiles, 512 blocks (2/CU); k_gram2 ->
// 128x64 tiles, 1024 blocks (4/CU). Same c0->k FMA order per output => bitwise-identical.
extern "C" void kernel_launch(void* const* d_in, const int* in_sizes, int n_in,
                              void* d_out, int out_size, void* d_ws, size_t ws_size,
                              hipStream_t stream) {
  const float* x = (const float*)d_in[0];
  const float* y = (const float*)d_in[1];
  const float* w1 = (const float*)d_in[2];
  const float* w2 = (const float*)d_in[3];
  const float* w3 = (const float*)d_in[4];
  const float* w4 = (const float*)d_in[5];
  const float* w5 = (const float*)d_in[6];
  const float* g1 = (const float*)d_in[7];
  const float* b1 = (const float*)d_in[8];
  const float* g2 = (const float*)d_in[9];
  const float* b2 = (const float*)d_in[10];
  const float* g3 = (const float*)d_in[11];
  const float* b3 = (const float*)d_in[12];
  const float* g4 = (const float*)d_in[13];
  const float* b4 = (const float*)d_in[14];
  const float* g5 = (const float*)d_in[15];
  const float* b5 = (const float*)d_in[16];

  char* base = (char*)d_ws;
  size_t off = 0;
  auto alloc = [&](size_t bytes) -> char* {
    char* p = base + off;
    off += (bytes + 255) & ~(size_t)255;
    return p;
  };
  double* st = (double*)alloc(1024 * 8);
  float* sc  = (float*)alloc(1024 * 4);
  double* sq  = (double*)alloc((size_t)BB * NN * 8);
  double* rnx = (double*)alloc((size_t)BB * NN * 8);
  double* rny = (double*)alloc((size_t)BB * MM * 8);
  int*   idxb = (int*)alloc((size_t)BB * NN * KNN * 4);
  float* xs3 = (float*)alloc((size_t)BB * NN * 3 * 4);
  float* ys  = (float*)alloc((size_t)BB * MM * 128 * 4);
  float* cat = (float*)alloc((size_t)BB * NN * 512 * 4);
  size_t ddBatchBytes = (size_t)NN * MM * 8;  // 8 MB per batch (f64)
  size_t avail = (ws_size > off) ? (ws_size - off) : 0;
  int CB = (int)(avail / ddBatchBytes);
  if (CB < 1) CB = 1;
  if (CB > BB) CB = BB;
  char*  U   = alloc((size_t)CB * ddBatchBytes);
  double* DD = (double*)U;                     // dist/simi chunk (f64), dead after topk
  float* tt  = (float*)U;                      // center term (f32, <=8MB), after DD dead
  float* y5  = (float*)U;                      // layer-5 pre-BN (16MB, needs CB>=2)
  float* uu  = (float*)d_out;                  // source term (<=8MB)
  float* mx  = (float*)d_out + (size_t)2 * 1024 * 1024;  // max_k y (<=8MB)
  float* outp = (float*)d_out;

  const dim3 blk2(16, 16);
  const double cntE = (double)BB * NN * KNN;

  // knn: sym=1 -> triangular symmetric euclid gram (A==B); else general 128x64 MODE
  auto knn = [&](const float* A, int lda, const float* Bm, int ldb,
                 const double* sa, const double* sb, int C, int mode, int sym) {
    for (int b0 = 0; b0 < BB; b0 += CB) {
      int cb = (BB - b0 < CB) ? (BB - b0) : CB;
      if (sym) {
        k_gram_sym<<<dim3(cb, 136), blk2, 0, stream>>>(A, lda, sa, DD, C, b0);
      } else {
        dim3 g(cb, MM / 64, NN / 128);
        if (mode == 1) k_gram2<1><<<g, blk2, 0, stream>>>(A, lda, Bm, ldb, sa, sb, DD, C, b0);
        else           k_gram2<2><<<g, blk2, 0, stream>>>(A, lda, Bm, ldb, sa, sb, DD, C, b0);
      }
      k_topk<<<dim3(cb, 256), 256, 0, stream>>>(DD, idxb, b0);
    }
  };

  auto edge_layer = [&](const float* ctr, int ldc, const float* src, int ldsrc, int srcNp,
                        const float* w, int CW, const float* g, const float* bb,
                        int C, int O, int coff) {
    k_featmm<<<dim3(8, O / 64, 16), blk2, 0, stream>>>(src, ldsrc, w, CW, uu, C, O, 0, srcNp);
    k_featmm<<<dim3(8, O / 64, 16), blk2, 0, stream>>>(ctr, ldc, w, CW, tt, C, O, 1, NN);
    hipMemsetAsync(st, 0, 1024 * 8, stream);
    k_gather<<<dim3(BB, NN / 16, O / 64), 256, 0, stream>>>(uu, tt, idxb, st, mx, O, srcNp);
    k_bnfin<<<1, O, 0, stream>>>(st, g, bb, sc, O, cntE);
    k_bnapply<<<(BB * NN * O + 255) / 256, 256, 0, stream>>>(mx, uu, tt, idxb, sc, cat,
                                                             coff, O, srcNp);
  };

  // ---- input transposes ----
  k_transpose<<<96, 256, 0, stream>>>(x, xs3, 3, NN);
  k_transpose<<<2048, 256, 0, stream>>>(y, ys, 128, MM);

  // ---- layer 1: C=3, O=64 (fused knn, no DD) ----
  k_rowsq<0><<<32, 256, 0, stream>>>(xs3, 3, 3, sq);
  k_knn3<<<dim3(BB, 256), 256, 0, stream>>>(xs3, sq, idxb);
  edge_layer(xs3, 3, xs3, 3, NN, w1, 6, g1, b1, 3, 64, 0);

  // ---- layer 2: x1 = cat[:,0:64], C=64, O=64 ----
  k_rowsq<0><<<32, 256, 0, stream>>>(cat, 512, 64, sq);
  knn(cat, 512, cat, 512, sq, sq, 64, 1, 1);
  edge_layer(cat, 512, cat, 512, NN, w2, 128, g2, b2, 64, 64, 64);

  // ---- layer 3: x2 = cat[:,64:128], C=64, O=128 ----
  k_rowsq<0><<<32, 256, 0, stream>>>(cat + 64, 512, 64, sq);
  knn(cat + 64, 512, cat + 64, 512, sq, sq, 64, 1, 1);
  edge_layer(cat + 64, 512, cat + 64, 512, NN, w3, 128, g3, b3, 64, 128, 128);

  // ---- layer 4 (IA): x3 = cat[:,128:256], src = y (cosine knn), C=128, O=256 ----
  k_rowsq<1><<<32, 256, 0, stream>>>(cat + 128, 512, 128, rnx);
  k_rowsq<1><<<32, 256, 0, stream>>>(ys, 128, 128, rny);
  knn(cat + 128, 512, ys, 128, rnx, rny, 128, 2, 0);
  edge_layer(cat + 128, 512, ys, 128, MM, w4, 256, g4, b4, 128, 256, 256);

  // ---- layer 5: GEMM (C=512,O=512) -> y5, BN over (B,N), lrelu, transposed out ----
  hipMemsetAsync(st, 0, 1024 * 8, stream);
  if (CB >= 2) {
    k_gemm5<<<dim3(8, 8, 8), blk2, 0, stream>>>(cat, w5, y5);
    k_stats512<<<dim3(32, 8), 256, 0, stream>>>(y5, st);
    k_bnfin<<<1, 512, 0, stream>>>(st, g5, b5, sc, 512, (double)(BB * NN));
    k_final5b<<<dim3(16, 8, 8), 256, 0, stream>>>(y5, sc, outp);
  } else {
    k_mmstats<<<dim3(8, 16, 8), blk2, 0, stream>>>(cat, w5, st);
    k_bnfin<<<1, 512, 0, stream>>>(st, g5, b5, sc, 512, (double)(BB * NN));
    k_final5<<<dim3(8, 16, 8), blk2, 0, stream>>>(cat, w5, sc, outp);
  }
}